// Round 3
// baseline (537.698 us; speedup 1.0000x reference)
//
#include <hip/hip_runtime.h>
#include <math.h>

// B=64, N=27, D=512. EPS=1e-5.
// Identity: both cross-attns have K/V constant along key axis -> uniform
// softmax -> output == the V row. All N^2 tensors are broadcasts of (B,D)
// vectors; msg BN stats decompose into per-i/per-j sums + a 27x27 Gram.
// Structure: 2 dispatches. (1) bf16 MFMA GEMM x@{A1,B1,V1,U1}^T -> Yb,
// also zeroes the barrier counters. (2) mega_k: persistent 256-block kernel
// with 8 device-wide tree barriers doing the whole serial chain + epilogue.

#define EPSC 1e-5f
#define NBLK 256

typedef short short8 __attribute__((ext_vector_type(8)));
typedef float f32x4 __attribute__((ext_vector_type(4)));

// ---- workspace layout (float offsets) ----
#define YB_OFF      0          // 1728*2048
#define GF_OFF      3538944
#define G_OFF       3571712
#define FVG_OFF     3604480
#define HH_OFF      3637248
#define E0_OFF      3670016
#define EN_OFF      3702784
#define EE_OFF      3735552
#define XN_OFF      3768320    // 64*27*512
#define PAC_OFF     4653056    // 256*736
#define SUMS_OFF    4841472    // 256*112
#define SAC_OFF     4870144    // 128
#define SAEP_OFF    4870272    // 256*32
#define SCEP_OFF    4878464    // 256*32
#define SEP_OFF     4886656    // 512
#define SCALP_OFF   4887168    // 512
#define MTAB_OFF    4887680    // 736
#define RSTAB_OFF   4888416    // 736
#define PBN_OFF     4889152    // 256*64
#define BARS_OFF    4905536    // 8*272 uints

__device__ __forceinline__ unsigned short f2bf(float f) {
    unsigned int u = __float_as_uint(f);
    return (unsigned short)((u + 0x7FFFu + ((u >> 16) & 1u)) >> 16);
}

// ================= bf16 MFMA GEMM (proven in round 2) =================
__global__ __launch_bounds__(256) void mfma_gemm_k(const float* __restrict__ X,
        const float* __restrict__ W0, const float* __restrict__ W1,
        const float* __restrict__ W2, const float* __restrict__ W3,
        float* __restrict__ Y, unsigned* __restrict__ bars) {
    if (blockIdx.x == 0 && blockIdx.y == 0) {
        for (int i = threadIdx.x; i < 8 * 272; i += 256) bars[i] = 0u;
    }
    __shared__ __align__(16) unsigned short As[128 * 32];
    __shared__ __align__(16) unsigned short Bs[128 * 32];
    int t = threadIdx.x;
    int rb0 = blockIdx.x * 128;
    int n0 = blockIdx.y * 128;
    const float* Wsel;
    switch (blockIdx.y >> 2) {
        case 0: Wsel = W0; break; case 1: Wsel = W1; break;
        case 2: Wsel = W2; break; default: Wsel = W3; break;
    }
    int wrow0 = (blockIdx.y & 3) * 128;
    int tt = t & 127;
    int sr = (tt & 64) + (((tt & 1) << 5) | ((tt & 63) >> 1));
    bool isB = t >= 128;
    const float* src;
    bool valid;
    if (!isB) { int gr = rb0 + sr; valid = gr < 1728; src = X + (size_t)gr * 512; }
    else      { valid = true;      src = Wsel + (size_t)(wrow0 + sr) * 512; }
    unsigned short* dst = (isB ? Bs : As) + sr * 32;
    int rsh = (sr >> 1) & 3;
    int wave = t >> 6, l = t & 63;
    int wr = (wave >> 1) * 64, wc = (wave & 1) * 64;
    int lr = l & 15, g = l >> 4;
    f32x4 acc[4][4] = {};
    float4 v[8];
    float4 z4 = make_float4(0.f, 0.f, 0.f, 0.f);
#pragma unroll
    for (int i = 0; i < 8; i++) v[i] = valid ? ((const float4*)src)[i] : z4;
    for (int step = 0; step < 16; step++) {
        __syncthreads();
#pragma unroll
        for (int s = 0; s < 4; s++) {
            uint4 pk;
            pk.x = f2bf(v[2 * s].x) | ((unsigned)f2bf(v[2 * s].y) << 16);
            pk.y = f2bf(v[2 * s].z) | ((unsigned)f2bf(v[2 * s].w) << 16);
            pk.z = f2bf(v[2 * s + 1].x) | ((unsigned)f2bf(v[2 * s + 1].y) << 16);
            pk.w = f2bf(v[2 * s + 1].z) | ((unsigned)f2bf(v[2 * s + 1].w) << 16);
            *(uint4*)(dst + (((s + rsh) & 3) << 3)) = pk;
        }
        __syncthreads();
        if (step < 15) {
            const float4* nsrc = (const float4*)(src + (step + 1) * 32);
#pragma unroll
            for (int i = 0; i < 8; i++) v[i] = valid ? nsrc[i] : z4;
        }
        short8 af[4], bf[4];
#pragma unroll
        for (int m = 0; m < 4; m++) {
            int r = wr + m * 16 + lr;
            af[m] = *(const short8*)(As + r * 32 + (((g + (r >> 1)) & 3) << 3));
        }
#pragma unroll
        for (int n = 0; n < 4; n++) {
            int r = wc + n * 16 + lr;
            bf[n] = *(const short8*)(Bs + r * 32 + (((g + (r >> 1)) & 3) << 3));
        }
#pragma unroll
        for (int m = 0; m < 4; m++)
#pragma unroll
            for (int n = 0; n < 4; n++)
                acc[m][n] = __builtin_amdgcn_mfma_f32_16x16x32_bf16(af[m], bf[n], acc[m][n], 0, 0, 0);
    }
#pragma unroll
    for (int m = 0; m < 4; m++) {
        int row0 = rb0 + wr + m * 16 + g * 4;
#pragma unroll
        for (int reg = 0; reg < 4; reg++) {
            int row = row0 + reg;
            if (row < 1728) {
#pragma unroll
                for (int n = 0; n < 4; n++)
                    Y[(size_t)row * 2048 + n0 + wc + n * 16 + lr] = acc[m][n][reg];
            }
        }
    }
}

// ================= mega kernel =================
struct SmemA { float As[27][132]; float Cs[27][132]; };
struct SmemBF {
    float gfT[64][65];
    float WL[2][64];
    float part[128][2];
    float rowsumL[2];
    float eEL[128];
    float saeL[216];
    float sceL[216];
    float comb[4][8];
    float sp[2][2];
};
struct SmemH { float rstL[729]; float pmsL[729]; };
struct SmemJ { float jr[216][2]; float m2L[27]; float rs2L[27]; };

__device__ __forceinline__ void gbar(unsigned* bars, int k) {
    __threadfence();
    __syncthreads();
    if (threadIdx.x == 0) {
        unsigned* base = bars + k * 272;
        int g = blockIdx.x & 15;
        unsigned old = __hip_atomic_fetch_add(base + g * 16, 1u, __ATOMIC_ACQ_REL, __HIP_MEMORY_SCOPE_AGENT);
        if (old == 15u)
            __hip_atomic_fetch_add(base + 256, 1u, __ATOMIC_ACQ_REL, __HIP_MEMORY_SCOPE_AGENT);
        int spins = 0;
        while (__hip_atomic_load(base + 256, __ATOMIC_ACQUIRE, __HIP_MEMORY_SCOPE_AGENT) < 16u) {
            __builtin_amdgcn_s_sleep(8);
            if (++spins > 20000000) break;   // failsafe; never triggers when correct
        }
    }
    __syncthreads();
    __threadfence();
}

__device__ __forceinline__ float wred64(float v) {
#pragma unroll
    for (int o = 32; o; o >>= 1) v += __shfl_down(v, o, 64);
    return v;
}

// out[b, d0+dd] = epilogue( bias + sum_k in[b,k] W[d0+dd,k] ), d0 = blk*2
// mode 0: plain store. 1: batch-BN + relu. 2: store + scalar partials.
// 3: eE = rs*(dot - m*rowsum(W)) store + eEL stage.
__device__ void chain_gemm(const float* __restrict__ in, const float* __restrict__ W,
                           const float* __restrict__ bias, float* __restrict__ outp,
                           int mode, float m, float rs, float* __restrict__ scalarP,
                           SmemBF* S, int blk, int t) {
    int b = t & 63, dd = (t >> 6) & 1, kh = t >> 7;
    int d0 = blk * 2;
    float acc = 0.f, wsum = 0.f;
    const float4* in4 = (const float4*)in;
    float4 v[4];
    float wv = 0.f;
#pragma unroll
    for (int r = 0; r < 4; ++r) {
        int id = t + r * 256;
        v[r] = in4[(id >> 4) * 128 + (id & 15)];
    }
    if (t < 128) wv = W[(size_t)(d0 + dd) * 512 + b];
    for (int c = 0; c < 8; ++c) {
#pragma unroll
        for (int r = 0; r < 4; ++r) {
            int id = t + r * 256;
            int row = id >> 4, q = id & 15;
            int k4 = q * 4;
            S->gfT[k4 + 0][row] = v[r].x; S->gfT[k4 + 1][row] = v[r].y;
            S->gfT[k4 + 2][row] = v[r].z; S->gfT[k4 + 3][row] = v[r].w;
        }
        if (t < 128) { S->WL[dd][b] = wv; wsum += wv; }
        __syncthreads();
        if (c < 7) {
#pragma unroll
            for (int r = 0; r < 4; ++r) {
                int id = t + r * 256;
                v[r] = in4[(id >> 4) * 128 + (c + 1) * 16 + (id & 15)];
            }
            if (t < 128) wv = W[(size_t)(d0 + dd) * 512 + (c + 1) * 64 + b];
        }
        int k0 = kh * 32;
#pragma unroll
        for (int kk = 0; kk < 32; ++kk)
            acc = fmaf(S->gfT[k0 + kk][b], S->WL[dd][k0 + kk], acc);
        __syncthreads();
    }
    S->part[t & 127][kh] = acc;
    if (mode == 3 && t < 128) {
        float s = wred64(wsum);
        if ((t & 63) == 0) S->rowsumL[dd] = s;
    }
    __syncthreads();
    if (t < 128) {
        float tot = S->part[t][0] + S->part[t][1];
        if (bias) tot += bias[d0 + dd];
        int oidx = b * 512 + d0 + dd;
        if (mode == 0) {
            outp[oidx] = tot;
        } else if (mode == 1) {
            float s = tot, s2 = tot * tot;
#pragma unroll
            for (int o = 32; o; o >>= 1) { s += __shfl_down(s, o, 64); s2 += __shfl_down(s2, o, 64); }
            s = __shfl(s, 0, 64); s2 = __shfl(s2, 0, 64);
            float mm = s * (1.f / 64.f);
            float var = s2 * (1.f / 64.f) - mm * mm;
            float rr = 1.f / sqrtf(var + EPSC);
            outp[oidx] = fmaxf((tot - mm) * rr, 0.f);
        } else if (mode == 2) {
            outp[oidx] = tot;
            float s = tot, s2 = tot * tot;
#pragma unroll
            for (int o = 32; o; o >>= 1) { s += __shfl_down(s, o, 64); s2 += __shfl_down(s2, o, 64); }
            if ((t & 63) == 0) { S->sp[dd][0] = s; S->sp[dd][1] = s2; }
        } else {
            float val = rs * (tot - m * S->rowsumL[dd]);
            outp[oidx] = val;
            S->eEL[t] = val;
        }
    }
    if (mode == 2) {
        __syncthreads();
        if (t == 0) {
            scalarP[blk * 2]     = S->sp[0][0] + S->sp[1][0];
            scalarP[blk * 2 + 1] = S->sp[0][1] + S->sp[1][1];
        }
    }
    if (mode == 3) __syncthreads();
}

__global__ __launch_bounds__(256) void mega_k(const float* __restrict__ x,
        const float* __restrict__ gl_w, const float* __restrict__ gl_b,
        const float* __restrict__ fv_w, const float* __restrict__ fv_b,
        const float* __restrict__ av_w, const float* __restrict__ av_b,
        const float* __restrict__ ep_w, const float* __restrict__ ep_b,
        const float* __restrict__ E1, float* __restrict__ ws, float* __restrict__ out) {
    __shared__ __align__(16) char smem_raw[28544];
    int blk = blockIdx.x, t = threadIdx.x;

    float* Yb      = ws + YB_OFF;
    float* gf      = ws + GF_OFF;
    float* g       = ws + G_OFF;
    float* fvg     = ws + FVG_OFF;
    float* hh      = ws + HH_OFF;
    float* e0      = ws + E0_OFF;
    float* eN      = ws + EN_OFF;
    float* eE      = ws + EE_OFF;
    float* xn      = ws + XN_OFF;
    float* pac4    = ws + PAC_OFF;
    float* sums4   = ws + SUMS_OFF;
    float* SAC     = ws + SAC_OFF;
    float* saeP    = ws + SAEP_OFF;
    float* sceP    = ws + SCEP_OFF;
    float* seP     = ws + SEP_OFF;
    float* scalarP = ws + SCALP_OFF;
    float* mtab    = ws + MTAB_OFF;
    float* rstab   = ws + RSTAB_OFF;
    float* pbn     = ws + PBN_OFF;
    unsigned* bars = (unsigned*)(ws + BARS_OFF);

    // ---------- Phase A1: gf = mean_n x ----------
    if (t < 128) {
        int e = blk * 128 + t;
        int b = e >> 9, d = e & 511;
        const float* p = x + (size_t)b * 13824 + d;
        float s = 0.f;
#pragma unroll
        for (int n = 0; n < 27; n++) s += p[n << 9];
        gf[e] = s * (1.0f / 27.0f);
    }
    // ---------- Phase A2: Gram + a/c sum partials from Yb ----------
    {
        SmemA* SA = (SmemA*)smem_raw;
        int b = blk & 63, q = blk >> 6;   // q = 128-wide d-chunk
        for (int id = t; id < 864; id += 256) {
            int row = id >> 5, q4 = id & 31;
            size_t base = (size_t)(b * 27 + row) * 2048 + q * 128 + q4 * 4;
            *(float4*)&SA->As[row][q4 * 4] = *(const float4*)(Yb + base);
            *(float4*)&SA->Cs[row][q4 * 4] = *(const float4*)(Yb + base + 512);
        }
        __syncthreads();
        if (t < 243) {
            int i = t / 9, j0 = (t % 9) * 3;
            float a0 = 0, a1 = 0, a2 = 0;
#pragma unroll
            for (int k = 0; k < 128; k += 4) {
                float4 av = *(const float4*)&SA->As[i][k];
                float4 c0 = *(const float4*)&SA->Cs[j0][k];
                float4 c1 = *(const float4*)&SA->Cs[j0 + 1][k];
                float4 c2 = *(const float4*)&SA->Cs[j0 + 2][k];
                a0 += av.x * c0.x + av.y * c0.y + av.z * c0.z + av.w * c0.w;
                a1 += av.x * c1.x + av.y * c1.y + av.z * c1.z + av.w * c1.w;
                a2 += av.x * c2.x + av.y * c2.y + av.z * c2.z + av.w * c2.w;
            }
            float* prow = pac4 + (size_t)blk * 736 + i * 27 + j0;
            prow[0] = a0; prow[1] = a1; prow[2] = a2;
        }
        if (t < 27) {
            float s = 0, s2 = 0;
            for (int k = 0; k < 128; k++) { float vv = SA->As[t][k]; s += vv; s2 = fmaf(vv, vv, s2); }
            sums4[blk * 112 + t] = s; sums4[blk * 112 + 27 + t] = s2;
        } else if (t >= 32 && t < 59) {
            int i2 = t - 32;
            float s = 0, s2 = 0;
            for (int k = 0; k < 128; k++) { float vv = SA->Cs[i2][k]; s += vv; s2 = fmaf(vv, vv, s2); }
            sums4[blk * 112 + 54 + i2] = s; sums4[blk * 112 + 81 + i2] = s2;
        }
    }
    gbar(bars, 0);

    SmemBF* S = (SmemBF*)smem_raw;
    // ---------- Phase B: SAC reduce (blocks 0-3) + g0 gemm + batch-BN + relu ----------
    if (blk < 4 && t < 27) {
        float s = 0;
        for (int z = 0; z < 256; z++) s += sums4[z * 112 + blk * 27 + t];
        SAC[blk * 27 + t] = s;
    }
    chain_gemm(gf, gl_w, gl_b, g, 1, 0.f, 0.f, scalarP, S, blk, t);
    gbar(bars, 1);
    // ---------- Phase C/D/E ----------
    chain_gemm(g, fv_w, fv_b, fvg, 0, 0.f, 0.f, scalarP, S, blk, t);
    gbar(bars, 2);
    chain_gemm(fvg, av_w, av_b, hh, 0, 0.f, 0.f, scalarP, S, blk, t);
    gbar(bars, 3);
    chain_gemm(hh, ep_w, ep_b, e0, 2, 0.f, 0.f, scalarP, S, blk, t);
    gbar(bars, 4);
    // ---------- Phase F: scalar BN, eN, eE gemm, eE-dependent partials ----------
    {
        float sA = scalarP[2 * t], sB = scalarP[2 * t + 1];
        sA = wred64(sA); sB = wred64(sB);
        int wv_ = t >> 6;
        if ((t & 63) == 0) { S->comb[wv_][0] = sA; S->comb[wv_][1] = sB; }
        __syncthreads();
        float Ssum = S->comb[0][0] + S->comb[1][0] + S->comb[2][0] + S->comb[3][0];
        float S2sum = S->comb[0][1] + S->comb[1][1] + S->comb[2][1] + S->comb[3][1];
        float m = Ssum * (1.f / 32768.f);
        float var = S2sum * (1.f / 32768.f) - m * m;
        float rs = 1.f / sqrtf(var + EPSC);
        __syncthreads();
        if (t < 128) {
            int idx = (t & 63) * 512 + blk * 2 + (t >> 6);
            eN[idx] = (e0[idx] - m) * rs;
        }
        chain_gemm(e0, E1, nullptr, eE, 3, m, rs, scalarP, S, blk, t);
        // sae/sce partials over this block's 2 d-columns
        if (t < 216) {
            int i = t % 27, seg = t / 27;
            float sae = 0, sce = 0;
            for (int xq = seg * 16; xq < seg * 16 + 16; ++xq) {
                int bb = xq & 63, dd2 = xq >> 6;
                size_t base = (size_t)(bb * 27 + i) * 2048 + blk * 2 + dd2;
                float e = S->eEL[xq];
                sae = fmaf(Yb[base], e, sae);
                sce = fmaf(Yb[base + 512], e, sce);
            }
            S->saeL[i * 8 + seg] = sae;
            S->sceL[i * 8 + seg] = sce;
        }
        float ev = (t < 128) ? S->eEL[t] : 0.f;
        float es = wred64(ev), es2 = wred64(ev * ev);
        if ((t & 63) == 0) { S->comb[wv_][2] = es; S->comb[wv_][3] = es2; }
        __syncthreads();
        if (t == 0) {
            seP[blk * 2]     = S->comb[0][2] + S->comb[1][2] + S->comb[2][2] + S->comb[3][2];
            seP[blk * 2 + 1] = S->comb[0][3] + S->comb[1][3] + S->comb[2][3] + S->comb[3][3];
        }
        if (t < 27) {
            float s = 0;
            for (int sg2 = 0; sg2 < 8; sg2++) s += S->saeL[t * 8 + sg2];
            saeP[blk * 32 + t] = s;
        } else if (t >= 32 && t < 59) {
            float s = 0;
            for (int sg2 = 0; sg2 < 8; sg2++) s += S->sceL[(t - 32) * 8 + sg2];
            sceP[blk * 32 + (t - 32)] = s;
        }
    }
    gbar(bars, 5);
    // ---------- Phase G: finalize msg-BN tables (729 entries) ----------
    if (blk < 243) {
        for (int pp = 0; pp < 3; ++pp) {
            int p = blk * 3 + pp, i = p / 27, jm = p % 27;
            float v1 = pac4[(size_t)t * 736 + p];
            float v2 = saeP[t * 32 + i];
            float v3 = sceP[t * 32 + jm];
            float v4 = seP[2 * t], v5 = seP[2 * t + 1];
            v1 = wred64(v1); v2 = wred64(v2); v3 = wred64(v3); v4 = wred64(v4); v5 = wred64(v5);
            int wv_ = t >> 6;
            if ((t & 63) == 0) {
                S->comb[wv_][0] = v1; S->comb[wv_][1] = v2; S->comb[wv_][2] = v3;
                S->comb[wv_][3] = v4; S->comb[wv_][4] = v5;
            }
            __syncthreads();
            if (t == 0) {
                float sac = 0, sae = 0, sce = 0, se = 0, se2 = 0;
                for (int w2 = 0; w2 < 4; w2++) {
                    sac += S->comb[w2][0]; sae += S->comb[w2][1]; sce += S->comb[w2][2];
                    se += S->comb[w2][3]; se2 += S->comb[w2][4];
                }
                float Sa = SAC[i], Sa2 = SAC[27 + i], Sc = SAC[54 + jm], Sc2 = SAC[81 + jm];
                float mm = (Sa + Sc + se) * (1.f / 32768.f);
                float S2 = Sa2 + Sc2 + se2 + 2.f * (sac + sae + sce);
                float var = S2 * (1.f / 32768.f) - mm * mm;
                mtab[p] = mm;
                rstab[p] = 1.f / sqrtf(var + EPSC);
            }
            __syncthreads();
        }
    }
    gbar(bars, 6);
    // ---------- Phase H: fused gate/softmax/aggregate + per-n partials ----------
    {
        SmemH* SH = (SmemH*)smem_raw;
        for (int id = t; id < 729; id += 256) {
            float mm = mtab[id], rr = rstab[id];
            SH->rstL[id] = rr; SH->pmsL[id] = -mm * rr;
        }
        __syncthreads();
        int b = blk >> 2, ds4 = (blk & 3) * 128;
        int j = t & 127, ih = t >> 7;
        float ev = eE[b * 512 + ds4 + j], env = eN[b * 512 + ds4 + j];
        float cr[27], ur[27];
#pragma unroll
        for (int jj = 0; jj < 27; ++jj) {
            size_t rb = (size_t)(b * 27 + jj) * 2048 + ds4 + j;
            cr[jj] = Yb[rb + 512];
            ur[jj] = Yb[rb + 1024];
        }
        const float L2E = 1.4426950408889634f;
        int i0 = ih ? 14 : 0, i1 = ih ? 27 : 14;
        for (int i = i0; i < i1; ++i) {
            size_t rb = (size_t)(b * 27 + i) * 2048 + ds4 + j;
            float t1 = Yb[rb] + ev;
            const float* prst = SH->rstL + i * 27;
            const float* ppms = SH->pmsL + i * 27;
            float num = 0.f, den = 0.f;
#pragma unroll
            for (int jj = 0; jj < 27; ++jj) {
                float bn = fmaf(t1 + cr[jj], prst[jj], ppms[jj]);
                float r = fmaxf(bn, 0.f);
                float z = env + r;
                float tt = __builtin_amdgcn_exp2f(z * -L2E);
                float sg = __builtin_amdgcn_rcpf(1.f + tt);
                float w2 = __builtin_amdgcn_exp2f(sg * L2E);
                den += w2;
                num = fmaf(w2, ur[jj], num);
            }
            xn[(size_t)b * 13824 + i * 512 + ds4 + j] =
                Yb[rb + 1536] + num * __builtin_amdgcn_rcpf(den) * (1.f / 27.f);
        }
        __syncthreads();
        if (t < 27) {
            float s = 0, s2 = 0;
            const float4* xp = (const float4*)(xn + (size_t)b * 13824 + t * 512 + ds4);
            for (int q = 0; q < 32; q++) {
                float4 v = xp[q];
                s += (v.x + v.y) + (v.z + v.w);
                s2 += v.x * v.x + v.y * v.y + v.z * v.z + v.w * v.w;
            }
            pbn[blk * 64 + t * 2] = s;
            pbn[blk * 64 + t * 2 + 1] = s2;
        }
    }
    gbar(bars, 7);
    // ---------- Phase J: per-n BN finalize + residual relu out ----------
    {
        SmemJ* SJ = (SmemJ*)smem_raw;
        if (t < 216) {
            int n = t % 27, seg = t / 27;
            float s = 0, s2 = 0;
            for (int z = seg * 32; z < seg * 32 + 32; ++z) {
                s += pbn[z * 64 + n * 2];
                s2 += pbn[z * 64 + n * 2 + 1];
            }
            SJ->jr[t][0] = s; SJ->jr[t][1] = s2;
        }
        __syncthreads();
        if (t < 27) {
            float Ssum = 0, S2sum = 0;
            for (int sg2 = 0; sg2 < 8; sg2++) {
                Ssum += SJ->jr[sg2 * 27 + t][0];
                S2sum += SJ->jr[sg2 * 27 + t][1];
            }
            float mm = Ssum * (1.f / 32768.f);
            float var = S2sum * (1.f / 32768.f) - mm * mm;
            SJ->m2L[t] = mm;
            SJ->rs2L[t] = 1.f / sqrtf(var + EPSC);
        }
        __syncthreads();
        if (t < 128) {
            int b = blk >> 2, ds4 = (blk & 3) * 128, j = t;
            for (int n = 0; n < 27; ++n) {
                size_t xi = (size_t)b * 13824 + n * 512 + ds4 + j;
                float xv = x[xi], xnv = xn[xi];
                out[xi] = fmaxf(fmaf(xnv - SJ->m2L[n], SJ->rs2L[n], xv), 0.f);
            }
        }
    }
}

extern "C" void kernel_launch(void* const* d_in, const int* in_sizes, int n_in,
                              void* d_out, int out_size, void* d_ws, size_t ws_size,
                              hipStream_t stream) {
    const float* x    = (const float*)d_in[0];
    const float* gl_w = (const float*)d_in[1];
    const float* gl_b = (const float*)d_in[2];
    const float* fv_w = (const float*)d_in[7];
    const float* fv_b = (const float*)d_in[8];
    const float* av_w = (const float*)d_in[13];
    const float* av_b = (const float*)d_in[14];
    const float* ep_w = (const float*)d_in[15];
    const float* ep_b = (const float*)d_in[16];
    const float* U1   = (const float*)d_in[17];
    const float* V1   = (const float*)d_in[18];
    const float* A1   = (const float*)d_in[19];
    const float* B1   = (const float*)d_in[20];
    const float* E1   = (const float*)d_in[21];
    float* out = (float*)d_out;
    float* ws = (float*)d_ws;

    float* Yb = ws + YB_OFF;
    unsigned* bars = (unsigned*)(ws + BARS_OFF);

    mfma_gemm_k<<<dim3(14, 16), 256, 0, stream>>>(x, A1, B1, V1, U1, Yb, bars);
    mega_k<<<NBLK, 256, 0, stream>>>(x, gl_w, gl_b, fv_w, fv_b, av_w, av_b,
                                     ep_w, ep_b, E1, ws, out);
}

// Round 4
// 512.067 us; speedup vs baseline: 1.0501x; 1.0501x over previous
//
#include <hip/hip_runtime.h>
#include <math.h>

// B=64, N=27, D=512. EPS=1e-5.
// Identities: (1) both cross-attns have K/V constant along the key axis ->
// uniform softmax -> output == the V row; all N^2 tensors are broadcasts of
// (B,D) vectors. (2) msg BN stats decompose: per-i/per-j sums + 27x27 Gram.
// (3) the fv->av->ep linear chain collapses: e0 = g@(ep@av@fv)^T + bc, and
// eE = eN@E1^T = rs*(e0@E1^T - m*rowsum(E1)).
// 7 dispatches; independent jobs packed per dispatch via blockIdx ranges.
// Cross-stage reductions via device-scope float atomics (zeroed in D1).

#define EPSC 1e-5f

typedef short short8 __attribute__((ext_vector_type(8)));
typedef float f32x4 __attribute__((ext_vector_type(4)));

// ---- ws layout (float offsets) ----
#define YB_OFF   0u          // 1728*2048
#define GF_OFF   3538944u
#define G_OFF    3571712u
#define E0_OFF   3604480u
#define F0_OFF   3637248u
#define EN_OFF   3670016u
#define EE_OFF   3702784u
#define XN_OFF   3735552u    // 884736
#define T1_OFF   4620288u    // 262144
#define WC_OFF   4882432u    // 262144
#define BC0_OFF  5144576u
#define BC_OFF   5145088u
#define RE1_OFF  5145600u
#define PAC_OFF  5146112u    // 729 (atomic)
#define ST_OFF   5146848u    // 220 floats:
// ST: [0..27) Sa, [27..54) Sa2, [54..81) Sc, [81..108) Sc2,
//     [108..135) sae, [135..162) sce, [162] se, [163] se2,
//     [164..166) s_acc (atomic), [166..220) pbn_acc (atomic)

__device__ __forceinline__ unsigned short f2bf(float f) {
    unsigned int u = __float_as_uint(f);
    return (unsigned short)((u + 0x7FFFu + ((u >> 16) & 1u)) >> 16);
}

__device__ __forceinline__ float wred64(float v) {
#pragma unroll
    for (int o = 32; o; o >>= 1) v += __shfl_down(v, o, 64);
    return v;
}

// ============ job: bf16 MFMA GEMM Yb (proven R2) ============
__device__ void mfma_job(const float* __restrict__ X,
        const float* __restrict__ W0, const float* __restrict__ W1,
        const float* __restrict__ W2, const float* __restrict__ W3,
        float* __restrict__ Y, int bx, int by, int t, char* sbuf) {
    unsigned short* As = (unsigned short*)sbuf;          // 128*32
    unsigned short* Bs = As + 128 * 32;
    int rb0 = bx * 128;
    int n0 = by * 128;
    const float* Wsel;
    switch (by >> 2) {
        case 0: Wsel = W0; break; case 1: Wsel = W1; break;
        case 2: Wsel = W2; break; default: Wsel = W3; break;
    }
    int wrow0 = (by & 3) * 128;
    int tt = t & 127;
    int sr = (tt & 64) + (((tt & 1) << 5) | ((tt & 63) >> 1));
    bool isB = t >= 128;
    const float* src;
    bool valid;
    if (!isB) { int gr = rb0 + sr; valid = gr < 1728; src = X + (size_t)gr * 512; }
    else      { valid = true;      src = Wsel + (size_t)(wrow0 + sr) * 512; }
    unsigned short* dst = (isB ? Bs : As) + sr * 32;
    int rsh = (sr >> 1) & 3;
    int wave = t >> 6, l = t & 63;
    int wr = (wave >> 1) * 64, wc = (wave & 1) * 64;
    int lr = l & 15, g = l >> 4;
    f32x4 acc[4][4] = {};
    float4 v[8];
    float4 z4 = make_float4(0.f, 0.f, 0.f, 0.f);
#pragma unroll
    for (int i = 0; i < 8; i++) v[i] = valid ? ((const float4*)src)[i] : z4;
    for (int step = 0; step < 16; step++) {
        __syncthreads();
#pragma unroll
        for (int s = 0; s < 4; s++) {
            uint4 pk;
            pk.x = f2bf(v[2 * s].x) | ((unsigned)f2bf(v[2 * s].y) << 16);
            pk.y = f2bf(v[2 * s].z) | ((unsigned)f2bf(v[2 * s].w) << 16);
            pk.z = f2bf(v[2 * s + 1].x) | ((unsigned)f2bf(v[2 * s + 1].y) << 16);
            pk.w = f2bf(v[2 * s + 1].z) | ((unsigned)f2bf(v[2 * s + 1].w) << 16);
            *(uint4*)(dst + (((s + rsh) & 3) << 3)) = pk;
        }
        __syncthreads();
        if (step < 15) {
            const float4* nsrc = (const float4*)(src + (step + 1) * 32);
#pragma unroll
            for (int i = 0; i < 8; i++) v[i] = valid ? nsrc[i] : z4;
        }
        short8 af[4], bf[4];
#pragma unroll
        for (int m = 0; m < 4; m++) {
            int r = wr + m * 16 + lr;
            af[m] = *(const short8*)(As + r * 32 + (((g + (r >> 1)) & 3) << 3));
        }
#pragma unroll
        for (int n = 0; n < 4; n++) {
            int r = wc + n * 16 + lr;
            bf[n] = *(const short8*)(Bs + r * 32 + (((g + (r >> 1)) & 3) << 3));
        }
#pragma unroll
        for (int m = 0; m < 4; m++)
#pragma unroll
            for (int n = 0; n < 4; n++)
                acc[m][n] = __builtin_amdgcn_mfma_f32_16x16x32_bf16(af[m], bf[n], acc[m][n], 0, 0, 0);
    }
#pragma unroll
    for (int m = 0; m < 4; m++) {
        int row0 = rb0 + wr + m * 16 + g * 4;
#pragma unroll
        for (int reg = 0; reg < 4; reg++) {
            int row = row0 + reg;
            if (row < 1728) {
#pragma unroll
                for (int n = 0; n < 4; n++)
                    Y[(size_t)row * 2048 + n0 + wc + n * 16 + lr] = acc[m][n][reg];
            }
        }
    }
}

// ============ job: fp32 64x64-tile GEMM C[i,j] = sum_k A[i,k]*B[k,j] ============
// M=N=K=512, grid 8x8 per matrix.
__device__ void vgemm_job(const float* __restrict__ A, const float* __restrict__ Bm,
                          float* __restrict__ C, int bi, int bj, int t, char* sbuf) {
    float* Xs = (float*)sbuf;        // [16][68]
    float* Bs = Xs + 16 * 68;        // [16][68]
    int lrow = t >> 2, lk4 = (t & 3) * 4;
    int krow = t >> 4, jc = (t & 15) * 4;
    int tm = (t >> 4) * 4, tn = (t & 15) * 4;
    float acc[4][4] = {};
    for (int k0 = 0; k0 < 512; k0 += 16) {
        float4 av = *(const float4*)(A + (size_t)(bi * 64 + lrow) * 512 + k0 + lk4);
        float4 bv = *(const float4*)(Bm + (size_t)(k0 + krow) * 512 + bj * 64 + jc);
        Xs[(lk4 + 0) * 68 + lrow] = av.x; Xs[(lk4 + 1) * 68 + lrow] = av.y;
        Xs[(lk4 + 2) * 68 + lrow] = av.z; Xs[(lk4 + 3) * 68 + lrow] = av.w;
        *(float4*)&Bs[krow * 68 + jc] = bv;
        __syncthreads();
#pragma unroll
        for (int kk = 0; kk < 16; kk++) {
            float4 xa = *(const float4*)&Xs[kk * 68 + tm];
            float4 wb = *(const float4*)&Bs[kk * 68 + tn];
            float xr[4] = {xa.x, xa.y, xa.z, xa.w};
            float wr[4] = {wb.x, wb.y, wb.z, wb.w};
#pragma unroll
            for (int ii = 0; ii < 4; ii++)
#pragma unroll
                for (int jj = 0; jj < 4; jj++)
                    acc[ii][jj] = fmaf(xr[ii], wr[jj], acc[ii][jj]);
        }
        __syncthreads();
    }
    for (int ii = 0; ii < 4; ii++) {
        float4 o = {acc[ii][0], acc[ii][1], acc[ii][2], acc[ii][3]};
        *(float4*)(C + (size_t)(bi * 64 + tm + ii) * 512 + bj * 64 + tn) = o;
    }
}

// ============ job: matvec vout[d] = sum_k W[d,k] vin[k] + badd[d] ============
__device__ void matvec_job(const float* __restrict__ W, const float* __restrict__ vin,
                           const float* __restrict__ badd, float* __restrict__ vout,
                           int jb, int t, char* sbuf) {
    float* vs = (float*)sbuf;
    vs[t] = vin[t]; vs[256 + t] = vin[256 + t];
    __syncthreads();
    int d = jb * 256 + t;
    const float4* W4 = (const float4*)(W + (size_t)d * 512);
    const float4* v4 = (const float4*)vs;
    float a0 = 0, a1 = 0, a2 = 0, a3 = 0;
#pragma unroll 8
    for (int k = 0; k < 128; k++) {
        float4 wv = W4[k]; float4 xv = v4[k];
        a0 = fmaf(wv.x, xv.x, a0); a1 = fmaf(wv.y, xv.y, a1);
        a2 = fmaf(wv.z, xv.z, a2); a3 = fmaf(wv.w, xv.w, a3);
    }
    vout[d] = (a0 + a1) + (a2 + a3) + badd[d];
}

// ============ D1 ============
__global__ __launch_bounds__(256) void d1_k(const float* __restrict__ x,
        const float* __restrict__ A1, const float* __restrict__ B1,
        const float* __restrict__ V1, const float* __restrict__ U1,
        const float* __restrict__ av_w, const float* __restrict__ fv_w,
        const float* __restrict__ fv_b, const float* __restrict__ av_b,
        const float* __restrict__ E1, float* __restrict__ ws) {
    __shared__ __align__(16) char sbuf[16384];
    int blk = blockIdx.x, t = threadIdx.x;
    if (blk < 224) {
        mfma_job(x, A1, B1, V1, U1, ws + YB_OFF, blk % 14, blk / 14, t, sbuf);
    } else if (blk < 288) {
        int jb = blk - 224;
        vgemm_job(av_w, fv_w, ws + T1_OFF, jb >> 3, jb & 7, t, sbuf);
    } else if (blk < 304) {
        int jb = blk - 288;
        float* gf = ws + GF_OFF;
        for (int p = 0; p < 8; p++) {
            int q = jb * 2048 + p * 256 + t;
            int b = q >> 9, d = q & 511;
            const float* pp = x + (size_t)b * 13824 + d;
            float s = 0.f;
#pragma unroll
            for (int n = 0; n < 27; n++) s += pp[n << 9];
            gf[q] = s * (1.0f / 27.0f);
        }
    } else if (blk < 306) {
        matvec_job(av_w, fv_b, av_b, ws + BC0_OFF, blk - 304, t, sbuf);
    } else if (blk < 308) {
        int d = (blk - 306) * 256 + t;
        const float4* r4 = (const float4*)(E1 + (size_t)d * 512);
        float a0 = 0, a1 = 0, a2 = 0, a3 = 0;
#pragma unroll 8
        for (int k = 0; k < 128; k++) {
            float4 v = r4[k];
            a0 += v.x; a1 += v.y; a2 += v.z; a3 += v.w;
        }
        (ws + RE1_OFF)[d] = (a0 + a1) + (a2 + a3);
    } else {
        float* pac = ws + PAC_OFF;
        float* ST = ws + ST_OFF;
        for (int q = t; q < 729; q += 256) pac[q] = 0.f;
        if (t < 56) ST[164 + t] = 0.f;
    }
}

// ============ D2 jobs ============
__device__ void g_job(const float* __restrict__ gf, const float* __restrict__ gl_w,
                      const float* __restrict__ gl_b, float* __restrict__ g,
                      int jb, int t, char* sbuf) {
    float* gv = (float*)sbuf;    // [8][64]
    float* mrs = gv + 512;       // [16]
    int b = t >> 2, ds = t & 3;
    int d0 = jb * 8;
    const float4* A4 = (const float4*)(gf + (size_t)b * 512);
    for (int h = 0; h < 2; h++) {
        int d = d0 + h * 4 + ds;
        const float4* W4 = (const float4*)(gl_w + (size_t)d * 512);
        float a0 = 0, a1 = 0, a2 = 0, a3 = 0;
#pragma unroll 8
        for (int k = 0; k < 128; k++) {
            float4 av = A4[k]; float4 wv = W4[k];
            a0 = fmaf(av.x, wv.x, a0); a1 = fmaf(av.y, wv.y, a1);
            a2 = fmaf(av.z, wv.z, a2); a3 = fmaf(av.w, wv.w, a3);
        }
        gv[(h * 4 + ds) * 64 + b] = (a0 + a1) + (a2 + a3) + gl_b[d];
    }
    __syncthreads();
    if (t < 8) {
        float s = 0, s2 = 0;
        for (int bb = 0; bb < 64; bb++) { float v = gv[t * 64 + bb]; s += v; s2 = fmaf(v, v, s2); }
        float m = s * (1.f / 64.f);
        float var = s2 * (1.f / 64.f) - m * m;
        mrs[t] = m; mrs[8 + t] = 1.f / sqrtf(var + EPSC);
    }
    __syncthreads();
    for (int h = 0; h < 2; h++) {
        int dl = h * 4 + ds;
        float v = (gv[dl * 64 + b] - mrs[dl]) * mrs[8 + dl];
        g[b * 512 + d0 + dl] = fmaxf(v, 0.f);
    }
}

__device__ void gram_job(const float* __restrict__ Yb, float* __restrict__ pac,
                         int b, int t, char* sbuf) {
    float* As = (float*)sbuf;        // [27][132]
    float* Cs = As + 27 * 132;
    float a0 = 0, a1 = 0, a2 = 0;
    int i = t / 9, j0 = (t % 9) * 3;
    for (int dc = 0; dc < 4; dc++) {
        const float* base = Yb + (size_t)b * 27 * 2048 + dc * 128;
        for (int id = t; id < 864; id += 256) {
            int row = id >> 5, c4 = (id & 31) << 2;
            *(float4*)&As[row * 132 + c4] = *(const float4*)(base + (size_t)row * 2048 + c4);
            *(float4*)&Cs[row * 132 + c4] = *(const float4*)(base + (size_t)row * 2048 + 512 + c4);
        }
        __syncthreads();
        if (t < 243) {
#pragma unroll
            for (int k = 0; k < 128; k += 4) {
                float4 av = *(const float4*)&As[i * 132 + k];
                float4 c0 = *(const float4*)&Cs[j0 * 132 + k];
                float4 c1 = *(const float4*)&Cs[(j0 + 1) * 132 + k];
                float4 c2 = *(const float4*)&Cs[(j0 + 2) * 132 + k];
                a0 += av.x * c0.x + av.y * c0.y + av.z * c0.z + av.w * c0.w;
                a1 += av.x * c1.x + av.y * c1.y + av.z * c1.z + av.w * c1.w;
                a2 += av.x * c2.x + av.y * c2.y + av.z * c2.z + av.w * c2.w;
            }
        }
        __syncthreads();
    }
    if (t < 243) {
        atomicAdd(pac + i * 27 + j0, a0);
        atomicAdd(pac + i * 27 + j0 + 1, a1);
        atomicAdd(pac + i * 27 + j0 + 2, a2);
    }
}

__device__ void acsum_job(const float* __restrict__ Yb, float* __restrict__ ST,
                          int ia, int t, char* sbuf) {
    int i = ia < 27 ? ia : ia - 27;
    int off = ia < 27 ? 0 : 512;
    float s = 0, s2 = 0;
    for (int q = t; q < 32768; q += 256) {
        int b = q >> 9, d = q & 511;
        float v = Yb[(size_t)(b * 27 + i) * 2048 + off + d];
        s += v; s2 = fmaf(v, v, s2);
    }
    s = wred64(s); s2 = wred64(s2);
    float* p = (float*)sbuf;
    int wv_ = t >> 6;
    if ((t & 63) == 0) { p[wv_ * 2] = s; p[wv_ * 2 + 1] = s2; }
    __syncthreads();
    if (t == 0) {
        float S = p[0] + p[2] + p[4] + p[6];
        float S2 = p[1] + p[3] + p[5] + p[7];
        if (ia < 27) { ST[ia] = S; ST[27 + ia] = S2; }
        else { ST[54 + (ia - 27)] = S; ST[81 + (ia - 27)] = S2; }
    }
}

__global__ __launch_bounds__(256) void d2_k(const float* __restrict__ gl_w,
        const float* __restrict__ gl_b, const float* __restrict__ ep_w,
        const float* __restrict__ ep_b, float* __restrict__ ws) {
    __shared__ __align__(16) char sbuf[28544];
    int blk = blockIdx.x, t = threadIdx.x;
    if (blk < 64) {
        g_job(ws + GF_OFF, gl_w, gl_b, ws + G_OFF, blk, t, sbuf);
    } else if (blk < 128) {
        int jb = blk - 64;
        vgemm_job(ep_w, ws + T1_OFF, ws + WC_OFF, jb >> 3, jb & 7, t, sbuf);
    } else if (blk < 192) {
        gram_job(ws + YB_OFF, ws + PAC_OFF, blk - 128, t, sbuf);
    } else if (blk < 246) {
        acsum_job(ws + YB_OFF, ws + ST_OFF, blk - 192, t, sbuf);
    } else {
        matvec_job(ep_w, ws + BC0_OFF, ep_b, ws + BC_OFF, blk - 246, t, sbuf);
    }
}

// ============ D3/D4: dense (64x512 @ 512x512^T) ============
__device__ void dense_job(const float* __restrict__ A, const float* __restrict__ W,
                          const float* __restrict__ bias, float* __restrict__ Out,
                          int jb, int t, float* __restrict__ s_acc, char* sbuf,
                          bool doStats) {
    int b = t >> 2, ds = t & 3;
    int d0 = jb * 32;
    const float4* A4 = (const float4*)(A + (size_t)b * 512);
    float s = 0.f, s2 = 0.f;
    for (int dd = 0; dd < 8; dd++) {
        int d = d0 + dd * 4 + ds;
        const float4* W4 = (const float4*)(W + (size_t)d * 512);
        float a0 = 0, a1 = 0, a2 = 0, a3 = 0;
#pragma unroll 8
        for (int k = 0; k < 128; k++) {
            float4 av = A4[k]; float4 wv = W4[k];
            a0 = fmaf(av.x, wv.x, a0); a1 = fmaf(av.y, wv.y, a1);
            a2 = fmaf(av.z, wv.z, a2); a3 = fmaf(av.w, wv.w, a3);
        }
        float val = (a0 + a1) + (a2 + a3);
        if (bias) val += bias[d];
        Out[b * 512 + d] = val;
        s += val; s2 = fmaf(val, val, s2);
    }
    if (doStats) {
        s = wred64(s); s2 = wred64(s2);
        float* p = (float*)sbuf;
        int wv_ = t >> 6;
        if ((t & 63) == 0) { p[wv_ * 2] = s; p[wv_ * 2 + 1] = s2; }
        __syncthreads();
        if (t == 0) {
            atomicAdd(s_acc,     p[0] + p[2] + p[4] + p[6]);
            atomicAdd(s_acc + 1, p[1] + p[3] + p[5] + p[7]);
        }
    }
}

__global__ __launch_bounds__(256) void d3_k(float* __restrict__ ws) {
    __shared__ __align__(16) char sbuf[64];
    dense_job(ws + G_OFF, ws + WC_OFF, ws + BC_OFF, ws + E0_OFF,
              blockIdx.x, threadIdx.x, ws + ST_OFF + 164, sbuf, true);
}

__global__ __launch_bounds__(256) void d4_k(const float* __restrict__ E1, float* __restrict__ ws) {
    __shared__ __align__(16) char sbuf[64];
    dense_job(ws + E0_OFF, E1, nullptr, ws + F0_OFF,
              blockIdx.x, threadIdx.x, nullptr, sbuf, false);
}

// ============ D5: sae/sce/se + eE/eN ============
__global__ __launch_bounds__(256) void d5_k(float* __restrict__ ws) {
    __shared__ __align__(16) char sbuf[64];
    int ia = blockIdx.x, t = threadIdx.x;
    const float* Yb = ws + YB_OFF;
    const float* e0 = ws + E0_OFF;
    const float* f0 = ws + F0_OFF;
    const float* rE1 = ws + RE1_OFF;
    float* ST = ws + ST_OFF;
    float m = ST[164] * (1.f / 32768.f);
    float var = ST[165] * (1.f / 32768.f) - m * m;
    float rs = 1.f / sqrtf(var + EPSC);
    float s = 0, s2 = 0;
    if (ia < 54) {
        int i = ia < 27 ? ia : ia - 27;
        int off = ia < 27 ? 0 : 512;
        for (int q = t; q < 32768; q += 256) {
            int b = q >> 9, d = q & 511;
            float e = rs * (f0[q] - m * rE1[d]);
            s = fmaf(Yb[(size_t)(b * 27 + i) * 2048 + off + d], e, s);
        }
    } else {
        float* eE = ws + EE_OFF;
        float* eN = ws + EN_OFF;
        for (int q = t; q < 32768; q += 256) {
            int d = q & 511;
            float e = rs * (f0[q] - m * rE1[d]);
            eE[q] = e;
            eN[q] = (e0[q] - m) * rs;
            s += e; s2 = fmaf(e, e, s2);
        }
    }
    s = wred64(s); s2 = wred64(s2);
    float* p = (float*)sbuf;
    int wv_ = t >> 6;
    if ((t & 63) == 0) { p[wv_ * 2] = s; p[wv_ * 2 + 1] = s2; }
    __syncthreads();
    if (t == 0) {
        float S = p[0] + p[2] + p[4] + p[6];
        float S2 = p[1] + p[3] + p[5] + p[7];
        if (ia < 27) ST[108 + ia] = S;
        else if (ia < 54) ST[135 + (ia - 27)] = S;
        else { ST[162] = S; ST[163] = S2; }
    }
}

// ============ D6: fuse gate/softmax/aggregate ============
__global__ __launch_bounds__(256) void d6_k(float* __restrict__ ws) {
    __shared__ __align__(16) char sbuf[5888];
    int blk = blockIdx.x, t = threadIdx.x;
    const float* Yb = ws + YB_OFF;
    const float* eE = ws + EE_OFF;
    const float* eN = ws + EN_OFF;
    const float* pac = ws + PAC_OFF;
    float* ST = ws + ST_OFF;
    float* xn = ws + XN_OFF;
    float* pbn_acc = ST + 166;
    float* rstL = (float*)sbuf;      // 736
    float* pmsL = rstL + 736;
    float Se = ST[162], Se2 = ST[163];
    const float inv = 1.f / 32768.f;
    for (int id = t; id < 729; id += 256) {
        int i = id / 27, j = id - i * 27;
        float m = (ST[i] + ST[54 + j] + Se) * inv;
        float S2 = ST[27 + i] + ST[81 + j] + Se2 + 2.f * (pac[id] + ST[108 + i] + ST[135 + j]);
        float var = S2 * inv - m * m;
        float rst = 1.f / sqrtf(var + EPSC);
        rstL[id] = rst; pmsL[id] = -m * rst;
    }
    __syncthreads();
    int b = blk >> 2, ds4 = (blk & 3) * 128;
    int j = t & 127, ih = t >> 7;
    float ev = eE[b * 512 + ds4 + j], env = eN[b * 512 + ds4 + j];
    float cr[27], ur[27];
#pragma unroll
    for (int jj = 0; jj < 27; ++jj) {
        size_t rb = (size_t)(b * 27 + jj) * 2048 + ds4 + j;
        cr[jj] = Yb[rb + 512];
        ur[jj] = Yb[rb + 1024];
    }
    const float L2E = 1.4426950408889634f;
    int i0 = ih ? 14 : 0, i1 = ih ? 27 : 14;
    for (int i = i0; i < i1; ++i) {
        size_t rb = (size_t)(b * 27 + i) * 2048 + ds4 + j;
        float t1 = Yb[rb] + ev;
        const float* prst = rstL + i * 27;
        const float* ppms = pmsL + i * 27;
        float num = 0.f, den = 0.f;
#pragma unroll
        for (int jj = 0; jj < 27; ++jj) {
            float bn = fmaf(t1 + cr[jj], prst[jj], ppms[jj]);
            float r = fmaxf(bn, 0.f);
            float z = env + r;
            float tt = __builtin_amdgcn_exp2f(z * -L2E);
            float sg = __builtin_amdgcn_rcpf(1.f + tt);
            float w2 = __builtin_amdgcn_exp2f(sg * L2E);
            den += w2;
            num = fmaf(w2, ur[jj], num);
        }
        xn[(size_t)b * 13824 + i * 512 + ds4 + j] =
            Yb[rb + 1536] + num * __builtin_amdgcn_rcpf(den) * (1.f / 27.f);
    }
    __syncthreads();
    if (t < 27) {
        float s = 0, s2 = 0;
        const float4* xp = (const float4*)(xn + (size_t)b * 13824 + t * 512 + ds4);
        for (int q = 0; q < 32; q++) {
            float4 v = xp[q];
            s += (v.x + v.y) + (v.z + v.w);
            s2 += v.x * v.x + v.y * v.y + v.z * v.z + v.w * v.w;
        }
        atomicAdd(pbn_acc + t * 2, s);
        atomicAdd(pbn_acc + t * 2 + 1, s2);
    }
}

// ============ D7: per-n BN + residual relu ============
__global__ __launch_bounds__(256) void d7_k(const float* __restrict__ x,
        float* __restrict__ ws, float* __restrict__ out) {
    __shared__ __align__(16) char sbuf[256];
    int blk = blockIdx.x, t = threadIdx.x;
    const float* xn = ws + XN_OFF;
    const float* pbn_acc = ws + ST_OFF + 166;
    float* m2L = (float*)sbuf;
    float* rs2L = m2L + 32;
    if (t < 27) {
        float S = pbn_acc[t * 2], S2 = pbn_acc[t * 2 + 1];
        float m = S * (1.f / 32768.f);
        float var = S2 * (1.f / 32768.f) - m * m;
        m2L[t] = m; rs2L[t] = 1.f / sqrtf(var + EPSC);
    }
    __syncthreads();
    int b = blk >> 2, ds4 = (blk & 3) * 128;
    int j = t & 127, nh = t >> 7;
    int n0 = nh * 14, n1 = nh ? 27 : 14;
    for (int n = n0; n < n1; ++n) {
        size_t xi = (size_t)b * 13824 + n * 512 + ds4 + j;
        out[xi] = fmaxf(fmaf(xn[xi] - m2L[n], rs2L[n], x[xi]), 0.f);
    }
}

extern "C" void kernel_launch(void* const* d_in, const int* in_sizes, int n_in,
                              void* d_out, int out_size, void* d_ws, size_t ws_size,
                              hipStream_t stream) {
    const float* x    = (const float*)d_in[0];
    const float* gl_w = (const float*)d_in[1];
    const float* gl_b = (const float*)d_in[2];
    const float* fv_w = (const float*)d_in[7];
    const float* fv_b = (const float*)d_in[8];
    const float* av_w = (const float*)d_in[13];
    const float* av_b = (const float*)d_in[14];
    const float* ep_w = (const float*)d_in[15];
    const float* ep_b = (const float*)d_in[16];
    const float* U1   = (const float*)d_in[17];
    const float* V1   = (const float*)d_in[18];
    const float* A1   = (const float*)d_in[19];
    const float* B1   = (const float*)d_in[20];
    const float* E1   = (const float*)d_in[21];
    float* out = (float*)d_out;
    float* ws = (float*)d_ws;

    d1_k<<<309, 256, 0, stream>>>(x, A1, B1, V1, U1, av_w, fv_w, fv_b, av_b, E1, ws);
    d2_k<<<248, 256, 0, stream>>>(gl_w, gl_b, ep_w, ep_b, ws);
    d3_k<<<16, 256, 0, stream>>>(ws);
    d4_k<<<16, 256, 0, stream>>>(E1, ws);
    d5_k<<<55, 256, 0, stream>>>(ws);
    d6_k<<<256, 256, 0, stream>>>(ws);
    d7_k<<<256, 256, 0, stream>>>(x, ws, out);
}

// Round 5
// 264.193 us; speedup vs baseline: 2.0352x; 1.9382x over previous
//
#include <hip/hip_runtime.h>
#include <math.h>

// B=64, N=27, D=512. EPS=1e-5.
// Identities: (1) both cross-attns have K/V constant along the key axis ->
// uniform softmax -> output == the V row; all N^2 tensors are broadcasts of
// (B,D) vectors. (2) msg BN stats decompose: per-i/per-j sums + 27x27 Gram.
// (3) linear chains collapse: e0 = g@Wc^T + bc with Wc = ep@(av@fv);
//     f0 = e0@E1^T = g@Wd^T + bcE with Wd = (E1@ep)@(av@fv), bcE = E1@bc.
// 6 dispatches; independent jobs packed per dispatch via blockIdx ranges.
// Cross-stage reductions via device-scope float atomics (zeroed in D1).

#define EPSC 1e-5f

typedef short short8 __attribute__((ext_vector_type(8)));
typedef float f32x4 __attribute__((ext_vector_type(4)));

// ---- ws layout (float offsets) ----
#define YB_OFF   0u          // 1728*2048
#define GF_OFF   3538944u
#define G_OFF    3571712u
#define E0_OFF   3604480u
#define F0_OFF   3637248u
#define EN_OFF   3670016u
#define EE_OFF   3702784u
#define XN_OFF   3735552u    // 884736
#define T1_OFF   4620288u    // 262144
#define WC_OFF   4882432u    // 262144
#define WE_OFF   5144576u    // 262144
#define WD_OFF   5406720u    // 262144
#define BC0_OFF  5668864u
#define BC_OFF   5669376u
#define BCE_OFF  5669888u
#define RE1_OFF  5670400u
#define PAC_OFF  5670912u    // 729 (atomic)
#define ST_OFF   5671680u    // 220 floats:
// ST: [0..27) Sa, [27..54) Sa2, [54..81) Sc, [81..108) Sc2,
//     [108..135) sae, [135..162) sce, [162] se, [163] se2,
//     [164..166) s_acc (atomic), [166..220) pbn_acc (atomic)

__device__ __forceinline__ unsigned short f2bf(float f) {
    unsigned int u = __float_as_uint(f);
    return (unsigned short)((u + 0x7FFFu + ((u >> 16) & 1u)) >> 16);
}

__device__ __forceinline__ float wred64(float v) {
#pragma unroll
    for (int o = 32; o; o >>= 1) v += __shfl_down(v, o, 64);
    return v;
}

// ============ job: bf16 MFMA GEMM Yb (proven R2) ============
__device__ void mfma_job(const float* __restrict__ X,
        const float* __restrict__ W0, const float* __restrict__ W1,
        const float* __restrict__ W2, const float* __restrict__ W3,
        float* __restrict__ Y, int bx, int by, int t, char* sbuf) {
    unsigned short* As = (unsigned short*)sbuf;          // 128*32
    unsigned short* Bs = As + 128 * 32;
    int rb0 = bx * 128;
    int n0 = by * 128;
    const float* Wsel;
    switch (by >> 2) {
        case 0: Wsel = W0; break; case 1: Wsel = W1; break;
        case 2: Wsel = W2; break; default: Wsel = W3; break;
    }
    int wrow0 = (by & 3) * 128;
    int tt = t & 127;
    int sr = (tt & 64) + (((tt & 1) << 5) | ((tt & 63) >> 1));
    bool isB = t >= 128;
    const float* src;
    bool valid;
    if (!isB) { int gr = rb0 + sr; valid = gr < 1728; src = X + (size_t)gr * 512; }
    else      { valid = true;      src = Wsel + (size_t)(wrow0 + sr) * 512; }
    unsigned short* dst = (isB ? Bs : As) + sr * 32;
    int rsh = (sr >> 1) & 3;
    int wave = t >> 6, l = t & 63;
    int wr = (wave >> 1) * 64, wc = (wave & 1) * 64;
    int lr = l & 15, g = l >> 4;
    f32x4 acc[4][4] = {};
    float4 v[8];
    float4 z4 = make_float4(0.f, 0.f, 0.f, 0.f);
#pragma unroll
    for (int i = 0; i < 8; i++) v[i] = valid ? ((const float4*)src)[i] : z4;
    for (int step = 0; step < 16; step++) {
        __syncthreads();
#pragma unroll
        for (int s = 0; s < 4; s++) {
            uint4 pk;
            pk.x = f2bf(v[2 * s].x) | ((unsigned)f2bf(v[2 * s].y) << 16);
            pk.y = f2bf(v[2 * s].z) | ((unsigned)f2bf(v[2 * s].w) << 16);
            pk.z = f2bf(v[2 * s + 1].x) | ((unsigned)f2bf(v[2 * s + 1].y) << 16);
            pk.w = f2bf(v[2 * s + 1].z) | ((unsigned)f2bf(v[2 * s + 1].w) << 16);
            *(uint4*)(dst + (((s + rsh) & 3) << 3)) = pk;
        }
        __syncthreads();
        if (step < 15) {
            const float4* nsrc = (const float4*)(src + (step + 1) * 32);
#pragma unroll
            for (int i = 0; i < 8; i++) v[i] = valid ? nsrc[i] : z4;
        }
        short8 af[4], bf[4];
#pragma unroll
        for (int m = 0; m < 4; m++) {
            int r = wr + m * 16 + lr;
            af[m] = *(const short8*)(As + r * 32 + (((g + (r >> 1)) & 3) << 3));
        }
#pragma unroll
        for (int n = 0; n < 4; n++) {
            int r = wc + n * 16 + lr;
            bf[n] = *(const short8*)(Bs + r * 32 + (((g + (r >> 1)) & 3) << 3));
        }
#pragma unroll
        for (int m = 0; m < 4; m++)
#pragma unroll
            for (int n = 0; n < 4; n++)
                acc[m][n] = __builtin_amdgcn_mfma_f32_16x16x32_bf16(af[m], bf[n], acc[m][n], 0, 0, 0);
    }
#pragma unroll
    for (int m = 0; m < 4; m++) {
        int row0 = rb0 + wr + m * 16 + g * 4;
#pragma unroll
        for (int reg = 0; reg < 4; reg++) {
            int row = row0 + reg;
            if (row < 1728) {
#pragma unroll
                for (int n = 0; n < 4; n++)
                    Y[(size_t)row * 2048 + n0 + wc + n * 16 + lr] = acc[m][n][reg];
            }
        }
    }
}

// ============ job: fp32 64x64-tile GEMM C[i,j] = sum_k A[i,k]*B[k,j] ============
__device__ void vgemm_job(const float* __restrict__ A, const float* __restrict__ Bm,
                          float* __restrict__ C, int bi, int bj, int t, char* sbuf) {
    float* Xs = (float*)sbuf;        // [16][68]
    float* Bs = Xs + 16 * 68;        // [16][68]
    int lrow = t >> 2, lk4 = (t & 3) * 4;
    int krow = t >> 4, jc = (t & 15) * 4;
    int tm = (t >> 4) * 4, tn = (t & 15) * 4;
    float acc[4][4] = {};
    for (int k0 = 0; k0 < 512; k0 += 16) {
        float4 av = *(const float4*)(A + (size_t)(bi * 64 + lrow) * 512 + k0 + lk4);
        float4 bv = *(const float4*)(Bm + (size_t)(k0 + krow) * 512 + bj * 64 + jc);
        Xs[(lk4 + 0) * 68 + lrow] = av.x; Xs[(lk4 + 1) * 68 + lrow] = av.y;
        Xs[(lk4 + 2) * 68 + lrow] = av.z; Xs[(lk4 + 3) * 68 + lrow] = av.w;
        *(float4*)&Bs[krow * 68 + jc] = bv;
        __syncthreads();
#pragma unroll
        for (int kk = 0; kk < 16; kk++) {
            float4 xa = *(const float4*)&Xs[kk * 68 + tm];
            float4 wb = *(const float4*)&Bs[kk * 68 + tn];
            float xr[4] = {xa.x, xa.y, xa.z, xa.w};
            float wr[4] = {wb.x, wb.y, wb.z, wb.w};
#pragma unroll
            for (int ii = 0; ii < 4; ii++)
#pragma unroll
                for (int jj = 0; jj < 4; jj++)
                    acc[ii][jj] = fmaf(xr[ii], wr[jj], acc[ii][jj]);
        }
        __syncthreads();
    }
    for (int ii = 0; ii < 4; ii++) {
        float4 o = {acc[ii][0], acc[ii][1], acc[ii][2], acc[ii][3]};
        *(float4*)(C + (size_t)(bi * 64 + tm + ii) * 512 + bj * 64 + tn) = o;
    }
}

// ============ job: matvec vout[d] = sum_k W[d,k] vin[k] + badd[d] ============
__device__ void matvec_job(const float* __restrict__ W, const float* __restrict__ vin,
                           const float* __restrict__ badd, float* __restrict__ vout,
                           int jb, int t, char* sbuf) {
    float* vs = (float*)sbuf;
    vs[t] = vin[t]; vs[256 + t] = vin[256 + t];
    __syncthreads();
    int d = jb * 256 + t;
    const float4* W4 = (const float4*)(W + (size_t)d * 512);
    const float4* v4 = (const float4*)vs;
    float a0 = 0, a1 = 0, a2 = 0, a3 = 0;
#pragma unroll 8
    for (int k = 0; k < 128; k++) {
        float4 wv = W4[k]; float4 xv = v4[k];
        a0 = fmaf(wv.x, xv.x, a0); a1 = fmaf(wv.y, xv.y, a1);
        a2 = fmaf(wv.z, xv.z, a2); a3 = fmaf(wv.w, xv.w, a3);
    }
    vout[d] = (a0 + a1) + (a2 + a3) + badd[d];
}

// ============ job: vout[d] = WA[d,:]@va + WB[d,:]@vb ============
__device__ void matvec2_job(const float* __restrict__ WA, const float* __restrict__ va,
                            const float* __restrict__ WB, const float* __restrict__ vb,
                            float* __restrict__ vout, int jb, int t, char* sbuf) {
    float* vs = (float*)sbuf;
    vs[t] = va[t]; vs[256 + t] = va[256 + t];
    vs[512 + t] = vb[t]; vs[768 + t] = vb[256 + t];
    __syncthreads();
    int d = jb * 256 + t;
    const float4* A4 = (const float4*)(WA + (size_t)d * 512);
    const float4* B4 = (const float4*)(WB + (size_t)d * 512);
    const float4* va4 = (const float4*)vs;
    const float4* vb4 = (const float4*)(vs + 512);
    float a0 = 0, a1 = 0, a2 = 0, a3 = 0;
#pragma unroll 4
    for (int k = 0; k < 128; k++) {
        float4 wv = A4[k]; float4 xv = va4[k];
        a0 = fmaf(wv.x, xv.x, a0); a1 = fmaf(wv.y, xv.y, a1);
        a2 = fmaf(wv.z, xv.z, a2); a3 = fmaf(wv.w, xv.w, a3);
        float4 w2 = B4[k]; float4 x2 = vb4[k];
        a0 = fmaf(w2.x, x2.x, a0); a1 = fmaf(w2.y, x2.y, a1);
        a2 = fmaf(w2.z, x2.z, a2); a3 = fmaf(w2.w, x2.w, a3);
    }
    vout[d] = (a0 + a1) + (a2 + a3);
}

// ============ job: dense 64x512 @ (4 rows of W)^T, W staged in LDS ============
// Out[b, d0+dl] = A[b,:]@W[d0+dl,:] + bias; one thread per output.
__device__ void dense4_job(const float* __restrict__ A, const float* __restrict__ W,
                           const float* __restrict__ bias, float* __restrict__ Out,
                           int jb, int t, float* __restrict__ s_acc, char* sbuf,
                           bool doStats) {
    float* Wl = (float*)sbuf;            // 2048 floats
    float* red = Wl + 2048;              // 8 floats
    int d0 = jb * 4;
    const float4* Wg = (const float4*)(W + (size_t)d0 * 512);
    float4* Wl4 = (float4*)Wl;
    Wl4[t] = Wg[t];
    Wl4[t + 256] = Wg[t + 256];
    __syncthreads();
    int b = t & 63, dl = t >> 6;
    const float4* A4 = (const float4*)(A + (size_t)b * 512);
    const float4* Wr = (const float4*)(Wl + dl * 512);
    float a0 = 0, a1 = 0, a2 = 0, a3 = 0;
#pragma unroll 8
    for (int k = 0; k < 128; k++) {
        float4 av = A4[k]; float4 wv = Wr[k];
        a0 = fmaf(av.x, wv.x, a0); a1 = fmaf(av.y, wv.y, a1);
        a2 = fmaf(av.z, wv.z, a2); a3 = fmaf(av.w, wv.w, a3);
    }
    float val = (a0 + a1) + (a2 + a3);
    if (bias) val += bias[d0 + dl];
    Out[b * 512 + d0 + dl] = val;
    if (doStats) {
        float s = wred64(val), s2 = wred64(val * val);
        int wv_ = t >> 6;
        if ((t & 63) == 0) { red[wv_ * 2] = s; red[wv_ * 2 + 1] = s2; }
        __syncthreads();
        if (t == 0) {
            atomicAdd(s_acc,     red[0] + red[2] + red[4] + red[6]);
            atomicAdd(s_acc + 1, red[1] + red[3] + red[5] + red[7]);
        }
    }
}

// ============ D1 ============
__global__ __launch_bounds__(256) void d1_k(const float* __restrict__ x,
        const float* __restrict__ A1, const float* __restrict__ B1,
        const float* __restrict__ V1, const float* __restrict__ U1,
        const float* __restrict__ av_w, const float* __restrict__ fv_w,
        const float* __restrict__ fv_b, const float* __restrict__ av_b,
        const float* __restrict__ ep_w, const float* __restrict__ E1,
        float* __restrict__ ws) {
    __shared__ __align__(16) char sbuf[16384];
    int blk = blockIdx.x, t = threadIdx.x;
    if (blk < 224) {
        mfma_job(x, A1, B1, V1, U1, ws + YB_OFF, blk % 14, blk / 14, t, sbuf);
    } else if (blk < 288) {
        int jb = blk - 224;   // T1 = av_w @ fv_w
        vgemm_job(av_w, fv_w, ws + T1_OFF, jb >> 3, jb & 7, t, sbuf);
    } else if (blk < 352) {
        int jb = blk - 288;   // We = E1 @ ep_w
        vgemm_job(E1, ep_w, ws + WE_OFF, jb >> 3, jb & 7, t, sbuf);
    } else if (blk < 368) {
        int jb = blk - 352;
        float* gf = ws + GF_OFF;
        for (int p = 0; p < 8; p++) {
            int q = jb * 2048 + p * 256 + t;
            int b = q >> 9, d = q & 511;
            const float* pp = x + (size_t)b * 13824 + d;
            float s = 0.f;
#pragma unroll
            for (int n = 0; n < 27; n++) s += pp[n << 9];
            gf[q] = s * (1.0f / 27.0f);
        }
    } else if (blk < 370) {
        matvec_job(av_w, fv_b, av_b, ws + BC0_OFF, blk - 368, t, sbuf);
    } else if (blk < 372) {
        int d = (blk - 370) * 256 + t;   // rE1[d] = rowsum of E1
        const float4* r4 = (const float4*)(E1 + (size_t)d * 512);
        float a0 = 0, a1 = 0, a2 = 0, a3 = 0;
#pragma unroll 8
        for (int k = 0; k < 128; k++) {
            float4 v = r4[k];
            a0 += v.x; a1 += v.y; a2 += v.z; a3 += v.w;
        }
        (ws + RE1_OFF)[d] = (a0 + a1) + (a2 + a3);
    } else {
        float* pac = ws + PAC_OFF;
        float* ST = ws + ST_OFF;
        for (int q = t; q < 729; q += 256) pac[q] = 0.f;
        if (t < 56) ST[164 + t] = 0.f;
    }
}

// ============ D2 jobs ============
__device__ void g_job(const float* __restrict__ gf, const float* __restrict__ gl_w,
                      const float* __restrict__ gl_b, float* __restrict__ g,
                      int jb, int t, char* sbuf) {
    float* gv = (float*)sbuf;    // [8][64]
    float* mrs = gv + 512;       // [16]
    int b = t >> 2, ds = t & 3;
    int d0 = jb * 8;
    const float4* A4 = (const float4*)(gf + (size_t)b * 512);
    for (int h = 0; h < 2; h++) {
        int d = d0 + h * 4 + ds;
        const float4* W4 = (const float4*)(gl_w + (size_t)d * 512);
        float a0 = 0, a1 = 0, a2 = 0, a3 = 0;
#pragma unroll 8
        for (int k = 0; k < 128; k++) {
            float4 av = A4[k]; float4 wv = W4[k];
            a0 = fmaf(av.x, wv.x, a0); a1 = fmaf(av.y, wv.y, a1);
            a2 = fmaf(av.z, wv.z, a2); a3 = fmaf(av.w, wv.w, a3);
        }
        gv[(h * 4 + ds) * 64 + b] = (a0 + a1) + (a2 + a3) + gl_b[d];
    }
    __syncthreads();
    if (t < 8) {
        float s = 0, s2 = 0;
        for (int bb = 0; bb < 64; bb++) { float v = gv[t * 64 + bb]; s += v; s2 = fmaf(v, v, s2); }
        float m = s * (1.f / 64.f);
        float var = s2 * (1.f / 64.f) - m * m;
        mrs[t] = m; mrs[8 + t] = 1.f / sqrtf(var + EPSC);
    }
    __syncthreads();
    for (int h = 0; h < 2; h++) {
        int dl = h * 4 + ds;
        float v = (gv[dl * 64 + b] - mrs[dl]) * mrs[8 + dl];
        g[b * 512 + d0 + dl] = fmaxf(v, 0.f);
    }
}

__device__ void gram_job(const float* __restrict__ Yb, float* __restrict__ pac,
                         int b, int t, char* sbuf) {
    float* As = (float*)sbuf;        // [27][132]
    float* Cs = As + 27 * 132;
    float a0 = 0, a1 = 0, a2 = 0;
    int i = t / 9, j0 = (t % 9) * 3;
    for (int dc = 0; dc < 4; dc++) {
        const float* base = Yb + (size_t)b * 27 * 2048 + dc * 128;
        for (int id = t; id < 864; id += 256) {
            int row = id >> 5, c4 = (id & 31) << 2;
            *(float4*)&As[row * 132 + c4] = *(const float4*)(base + (size_t)row * 2048 + c4);
            *(float4*)&Cs[row * 132 + c4] = *(const float4*)(base + (size_t)row * 2048 + 512 + c4);
        }
        __syncthreads();
        if (t < 243) {
#pragma unroll
            for (int k = 0; k < 128; k += 4) {
                float4 av = *(const float4*)&As[i * 132 + k];
                float4 c0 = *(const float4*)&Cs[j0 * 132 + k];
                float4 c1 = *(const float4*)&Cs[(j0 + 1) * 132 + k];
                float4 c2 = *(const float4*)&Cs[(j0 + 2) * 132 + k];
                a0 += av.x * c0.x + av.y * c0.y + av.z * c0.z + av.w * c0.w;
                a1 += av.x * c1.x + av.y * c1.y + av.z * c1.z + av.w * c1.w;
                a2 += av.x * c2.x + av.y * c2.y + av.z * c2.z + av.w * c2.w;
            }
        }
        __syncthreads();
    }
    if (t < 243) {
        atomicAdd(pac + i * 27 + j0, a0);
        atomicAdd(pac + i * 27 + j0 + 1, a1);
        atomicAdd(pac + i * 27 + j0 + 2, a2);
    }
}

__device__ void acsum_job(const float* __restrict__ Yb, float* __restrict__ ST,
                          int ia, int t, char* sbuf) {
    int i = ia < 27 ? ia : ia - 27;
    int off = ia < 27 ? 0 : 512;
    float s = 0, s2 = 0;
    for (int q = t; q < 32768; q += 256) {
        int b = q >> 9, d = q & 511;
        float v = Yb[(size_t)(b * 27 + i) * 2048 + off + d];
        s += v; s2 = fmaf(v, v, s2);
    }
    s = wred64(s); s2 = wred64(s2);
    float* p = (float*)sbuf;
    int wv_ = t >> 6;
    if ((t & 63) == 0) { p[wv_ * 2] = s; p[wv_ * 2 + 1] = s2; }
    __syncthreads();
    if (t == 0) {
        float S = p[0] + p[2] + p[4] + p[6];
        float S2 = p[1] + p[3] + p[5] + p[7];
        if (ia < 27) { ST[ia] = S; ST[27 + ia] = S2; }
        else { ST[54 + (ia - 27)] = S; ST[81 + (ia - 27)] = S2; }
    }
}

__global__ __launch_bounds__(256) void d2_k(const float* __restrict__ gl_w,
        const float* __restrict__ gl_b, const float* __restrict__ ep_w,
        const float* __restrict__ ep_b, const float* __restrict__ E1,
        float* __restrict__ ws) {
    __shared__ __align__(16) char sbuf[28544];
    int blk = blockIdx.x, t = threadIdx.x;
    if (blk < 64) {
        g_job(ws + GF_OFF, gl_w, gl_b, ws + G_OFF, blk, t, sbuf);
    } else if (blk < 128) {
        int jb = blk - 64;    // Wc = ep_w @ T1
        vgemm_job(ep_w, ws + T1_OFF, ws + WC_OFF, jb >> 3, jb & 7, t, sbuf);
    } else if (blk < 192) {
        int jb = blk - 128;   // Wd = We @ T1
        vgemm_job(ws + WE_OFF, ws + T1_OFF, ws + WD_OFF, jb >> 3, jb & 7, t, sbuf);
    } else if (blk < 256) {
        gram_job(ws + YB_OFF, ws + PAC_OFF, blk - 192, t, sbuf);
    } else if (blk < 310) {
        acsum_job(ws + YB_OFF, ws + ST_OFF, blk - 256, t, sbuf);
    } else if (blk < 312) {
        matvec_job(ep_w, ws + BC0_OFF, ep_b, ws + BC_OFF, blk - 310, t, sbuf);
    } else {
        matvec2_job(ws + WE_OFF, ws + BC0_OFF, E1, ep_b, ws + BCE_OFF, blk - 312, t, sbuf);
    }
}

// ============ D3: e0 = g@Wc^T + bc (with stats) ; f0 = g@Wd^T + bcE ============
__global__ __launch_bounds__(256) void d3_k(float* __restrict__ ws) {
    __shared__ __align__(16) char sbuf[8256];
    int blk = blockIdx.x, t = threadIdx.x;
    if (blk < 128) {
        dense4_job(ws + G_OFF, ws + WC_OFF, ws + BC_OFF, ws + E0_OFF,
                   blk, t, ws + ST_OFF + 164, sbuf, true);
    } else {
        dense4_job(ws + G_OFF, ws + WD_OFF, ws + BCE_OFF, ws + F0_OFF,
                   blk - 128, t, nullptr, sbuf, false);
    }
}

// ============ D4: sae/sce/se + eE/eN ============
__global__ __launch_bounds__(256) void d4_k(float* __restrict__ ws) {
    __shared__ __align__(16) char sbuf[64];
    int ia = blockIdx.x, t = threadIdx.x;
    const float* Yb = ws + YB_OFF;
    const float* e0 = ws + E0_OFF;
    const float* f0 = ws + F0_OFF;
    const float* rE1 = ws + RE1_OFF;
    float* ST = ws + ST_OFF;
    float m = ST[164] * (1.f / 32768.f);
    float var = ST[165] * (1.f / 32768.f) - m * m;
    float rs = 1.f / sqrtf(var + EPSC);
    float s = 0, s2 = 0;
    if (ia < 54) {
        int i = ia < 27 ? ia : ia - 27;
        int off = ia < 27 ? 0 : 512;
        for (int q = t; q < 32768; q += 256) {
            int b = q >> 9, d = q & 511;
            float e = rs * (f0[q] - m * rE1[d]);
            s = fmaf(Yb[(size_t)(b * 27 + i) * 2048 + off + d], e, s);
        }
    } else {
        float* eE = ws + EE_OFF;
        float* eN = ws + EN_OFF;
        for (int q = t; q < 32768; q += 256) {
            int d = q & 511;
            float e = rs * (f0[q] - m * rE1[d]);
            eE[q] = e;
            eN[q] = (e0[q] - m) * rs;
            s += e; s2 = fmaf(e, e, s2);
        }
    }
    s = wred64(s); s2 = wred64(s2);
    float* p = (float*)sbuf;
    int wv_ = t >> 6;
    if ((t & 63) == 0) { p[wv_ * 2] = s; p[wv_ * 2 + 1] = s2; }
    __syncthreads();
    if (t == 0) {
        float S = p[0] + p[2] + p[4] + p[6];
        float S2 = p[1] + p[3] + p[5] + p[7];
        if (ia < 27) ST[108 + ia] = S;
        else if (ia < 54) ST[135 + (ia - 27)] = S;
        else { ST[162] = S; ST[163] = S2; }
    }
}

// ============ D5: fuse gate/softmax/aggregate ============
__global__ __launch_bounds__(256) void d5_k(float* __restrict__ ws) {
    __shared__ __align__(16) char sbuf[5888];
    int blk = blockIdx.x, t = threadIdx.x;
    const float* Yb = ws + YB_OFF;
    const float* eE = ws + EE_OFF;
    const float* eN = ws + EN_OFF;
    const float* pac = ws + PAC_OFF;
    float* ST = ws + ST_OFF;
    float* xn = ws + XN_OFF;
    float* pbn_acc = ST + 166;
    float* rstL = (float*)sbuf;      // 736
    float* pmsL = rstL + 736;
    float Se = ST[162], Se2 = ST[163];
    const float inv = 1.f / 32768.f;
    for (int id = t; id < 729; id += 256) {
        int i = id / 27, j = id - i * 27;
        float m = (ST[i] + ST[54 + j] + Se) * inv;
        float S2 = ST[27 + i] + ST[81 + j] + Se2 + 2.f * (pac[id] + ST[108 + i] + ST[135 + j]);
        float var = S2 * inv - m * m;
        float rst = 1.f / sqrtf(var + EPSC);
        rstL[id] = rst; pmsL[id] = -m * rst;
    }
    __syncthreads();
    int b = blk >> 2, ds4 = (blk & 3) * 128;
    int j = t & 127, ih = t >> 7;
    float ev = eE[b * 512 + ds4 + j], env = eN[b * 512 + ds4 + j];
    float cr[27], ur[27];
#pragma unroll
    for (int jj = 0; jj < 27; ++jj) {
        size_t rb = (size_t)(b * 27 + jj) * 2048 + ds4 + j;
        cr[jj] = Yb[rb + 512];
        ur[jj] = Yb[rb + 1024];
    }
    const float L2E = 1.4426950408889634f;
    int i0 = ih ? 14 : 0, i1 = ih ? 27 : 14;
    for (int i = i0; i < i1; ++i) {
        size_t rb = (size_t)(b * 27 + i) * 2048 + ds4 + j;
        float t1 = Yb[rb] + ev;
        const float* prst = rstL + i * 27;
        const float* ppms = pmsL + i * 27;
        float num = 0.f, den = 0.f;
#pragma unroll
        for (int jj = 0; jj < 27; ++jj) {
            float bn = fmaf(t1 + cr[jj], prst[jj], ppms[jj]);
            float r = fmaxf(bn, 0.f);
            float z = env + r;
            float tt = __builtin_amdgcn_exp2f(z * -L2E);
            float sg = __builtin_amdgcn_rcpf(1.f + tt);
            float w2 = __builtin_amdgcn_exp2f(sg * L2E);
            den += w2;
            num = fmaf(w2, ur[jj], num);
        }
        xn[(size_t)b * 13824 + i * 512 + ds4 + j] =
            Yb[rb + 1536] + num * __builtin_amdgcn_rcpf(den) * (1.f / 27.f);
    }
    __syncthreads();
    if (t < 27) {
        float s = 0, s2 = 0;
        const float4* xp = (const float4*)(xn + (size_t)b * 13824 + t * 512 + ds4);
        for (int q = 0; q < 32; q++) {
            float4 v = xp[q];
            s += (v.x + v.y) + (v.z + v.w);
            s2 += v.x * v.x + v.y * v.y + v.z * v.z + v.w * v.w;
        }
        atomicAdd(pbn_acc + t * 2, s);
        atomicAdd(pbn_acc + t * 2 + 1, s2);
    }
}

// ============ D6: per-n BN + residual relu ============
__global__ __launch_bounds__(256) void d6_k(const float* __restrict__ x,
        float* __restrict__ ws, float* __restrict__ out) {
    __shared__ __align__(16) char sbuf[256];
    int blk = blockIdx.x, t = threadIdx.x;
    const float* xn = ws + XN_OFF;
    const float* pbn_acc = ws + ST_OFF + 166;
    float* m2L = (float*)sbuf;
    float* rs2L = m2L + 32;
    if (t < 27) {
        float S = pbn_acc[t * 2], S2 = pbn_acc[t * 2 + 1];
        float m = S * (1.f / 32768.f);
        float var = S2 * (1.f / 32768.f) - m * m;
        m2L[t] = m; rs2L[t] = 1.f / sqrtf(var + EPSC);
    }
    __syncthreads();
    int b = blk >> 2, ds4 = (blk & 3) * 128;
    int j = t & 127, nh = t >> 7;
    int n0 = nh * 14, n1 = nh ? 27 : 14;
    for (int n = n0; n < n1; ++n) {
        size_t xi = (size_t)b * 13824 + n * 512 + ds4 + j;
        out[xi] = fmaxf(fmaf(xn[xi] - m2L[n], rs2L[n], x[xi]), 0.f);
    }
}

extern "C" void kernel_launch(void* const* d_in, const int* in_sizes, int n_in,
                              void* d_out, int out_size, void* d_ws, size_t ws_size,
                              hipStream_t stream) {
    const float* x    = (const float*)d_in[0];
    const float* gl_w = (const float*)d_in[1];
    const float* gl_b = (const float*)d_in[2];
    const float* fv_w = (const float*)d_in[7];
    const float* fv_b = (const float*)d_in[8];
    const float* av_w = (const float*)d_in[13];
    const float* av_b = (const float*)d_in[14];
    const float* ep_w = (const float*)d_in[15];
    const float* ep_b = (const float*)d_in[16];
    const float* U1   = (const float*)d_in[17];
    const float* V1   = (const float*)d_in[18];
    const float* A1   = (const float*)d_in[19];
    const float* B1   = (const float*)d_in[20];
    const float* E1   = (const float*)d_in[21];
    float* out = (float*)d_out;
    float* ws = (float*)d_ws;

    d1_k<<<373, 256, 0, stream>>>(x, A1, B1, V1, U1, av_w, fv_w, fv_b, av_b, ep_w, E1, ws);
    d2_k<<<314, 256, 0, stream>>>(gl_w, gl_b, ep_w, ep_b, E1, ws);
    d3_k<<<256, 256, 0, stream>>>(ws);
    d4_k<<<55, 256, 0, stream>>>(ws);
    d5_k<<<256, 256, 0, stream>>>(ws);
    d6_k<<<256, 256, 0, stream>>>(x, ws, out);
}

// Round 6
// 153.798 us; speedup vs baseline: 3.4961x; 1.7178x over previous
//
#include <hip/hip_runtime.h>
#include <math.h>

// B=64, N=27, D=512. EPS=1e-5.
// Identities: (1) both cross-attns have K/V constant along the key axis ->
// uniform softmax -> output == the V row; all N^2 tensors are broadcasts of
// (B,D) vectors. (2) msg BN stats decompose: per-i/per-j sums + 27x27 Gram.
// (3) linear chains collapse: e0 = g@Wc^T + bc with Wc = ep@(av@fv);
//     f0 = e0@E1^T = g@Wd^T + bcE with Wd = (E1@ep)@(av@fv), bcE = We@bc0+E1@ep_b.
// 7 dispatches. All global access patterns wave-coalesced; LDS staging
// double-buffered against global latency (R5 post-mortem: latency stalls).

#define EPSC 1e-5f

typedef short short8 __attribute__((ext_vector_type(8)));
typedef float f32x4 __attribute__((ext_vector_type(4)));

// ---- ws layout (float offsets) ----
#define YB_OFF   0u          // 1728*2048
#define GF_OFF   3538944u
#define G_OFF    3571712u
#define E0_OFF   3604480u
#define F0_OFF   3637248u
#define EN_OFF   3670016u
#define EE_OFF   3702784u
#define XN_OFF   3735552u    // 884736
#define T1_OFF   4620288u    // 262144
#define WC_OFF   4882432u    // 262144
#define WE_OFF   5144576u    // 262144
#define WD_OFF   5406720u    // 262144
#define BC0_OFF  5668864u
#define BC_OFF   5669376u
#define BCE_OFF  5669888u
#define RE1_OFF  5670400u
#define PAC_OFF  5670912u    // 729 (atomic)
#define ST_OFF   5671680u    // 220 floats
// ST: [0..27) Sa, [27..54) Sa2, [54..81) Sc, [81..108) Sc2,
//     [108..135) sae(at), [135..162) sce(at), [162..164) se,se2(at),
//     [164..166) s_acc(at), [166..220) pbn_acc(at)

__device__ __forceinline__ unsigned short f2bf(float f) {
    unsigned int u = __float_as_uint(f);
    return (unsigned short)((u + 0x7FFFu + ((u >> 16) & 1u)) >> 16);
}

__device__ __forceinline__ float wred64(float v) {
#pragma unroll
    for (int o = 32; o; o >>= 1) v += __shfl_down(v, o, 64);
    return v;
}

// ============ D0: bf16 MFMA GEMM Yb (proven R2; prefetch moved earlier) ============
__global__ __launch_bounds__(256) void d0_k(const float* __restrict__ X,
        const float* __restrict__ W0, const float* __restrict__ W1,
        const float* __restrict__ W2, const float* __restrict__ W3,
        float* __restrict__ Y) {
    __shared__ __align__(16) unsigned short As[128 * 32];
    __shared__ __align__(16) unsigned short Bs[128 * 32];
    int t = threadIdx.x;
    int bx = blockIdx.x % 14, by = blockIdx.x / 14;
    int rb0 = bx * 128;
    int n0 = by * 128;
    const float* Wsel;
    switch (by >> 2) {
        case 0: Wsel = W0; break; case 1: Wsel = W1; break;
        case 2: Wsel = W2; break; default: Wsel = W3; break;
    }
    int wrow0 = (by & 3) * 128;
    int tt = t & 127;
    int sr = (tt & 64) + (((tt & 1) << 5) | ((tt & 63) >> 1));
    bool isB = t >= 128;
    const float* src;
    bool valid;
    if (!isB) { int gr = rb0 + sr; valid = gr < 1728; src = X + (size_t)gr * 512; }
    else      { valid = true;      src = Wsel + (size_t)(wrow0 + sr) * 512; }
    unsigned short* dst = (isB ? Bs : As) + sr * 32;
    int rsh = (sr >> 1) & 3;
    int wave = t >> 6, l = t & 63;
    int wr = (wave >> 1) * 64, wc = (wave & 1) * 64;
    int lr = l & 15, g = l >> 4;
    f32x4 acc[4][4] = {};
    float4 v[8];
    float4 z4 = make_float4(0.f, 0.f, 0.f, 0.f);
#pragma unroll
    for (int i = 0; i < 8; i++) v[i] = valid ? ((const float4*)src)[i] : z4;
    for (int step = 0; step < 16; step++) {
        __syncthreads();
#pragma unroll
        for (int s = 0; s < 4; s++) {
            uint4 pk;
            pk.x = f2bf(v[2 * s].x) | ((unsigned)f2bf(v[2 * s].y) << 16);
            pk.y = f2bf(v[2 * s].z) | ((unsigned)f2bf(v[2 * s].w) << 16);
            pk.z = f2bf(v[2 * s + 1].x) | ((unsigned)f2bf(v[2 * s + 1].y) << 16);
            pk.w = f2bf(v[2 * s + 1].z) | ((unsigned)f2bf(v[2 * s + 1].w) << 16);
            *(uint4*)(dst + (((s + rsh) & 3) << 3)) = pk;
        }
        if (step < 15) {   // prefetch BEFORE the compute barrier: in flight
            const float4* nsrc = (const float4*)(src + (step + 1) * 32);
#pragma unroll
            for (int i = 0; i < 8; i++) v[i] = valid ? nsrc[i] : z4;
        }
        __syncthreads();
        short8 af[4], bf[4];
#pragma unroll
        for (int m = 0; m < 4; m++) {
            int r = wr + m * 16 + lr;
            af[m] = *(const short8*)(As + r * 32 + (((g + (r >> 1)) & 3) << 3));
        }
#pragma unroll
        for (int n = 0; n < 4; n++) {
            int r = wc + n * 16 + lr;
            bf[n] = *(const short8*)(Bs + r * 32 + (((g + (r >> 1)) & 3) << 3));
        }
#pragma unroll
        for (int m = 0; m < 4; m++)
#pragma unroll
            for (int n = 0; n < 4; n++)
                acc[m][n] = __builtin_amdgcn_mfma_f32_16x16x32_bf16(af[m], bf[n], acc[m][n], 0, 0, 0);
    }
#pragma unroll
    for (int m = 0; m < 4; m++) {
        int row0 = rb0 + wr + m * 16 + g * 4;
#pragma unroll
        for (int reg = 0; reg < 4; reg++) {
            int row = row0 + reg;
            if (row < 1728) {
#pragma unroll
                for (int n = 0; n < 4; n++)
                    Y[(size_t)row * 2048 + n0 + wc + n * 16 + lr] = acc[m][n][reg];
            }
        }
    }
}

// ============ job: fp32 64x64 GEMM tile, double-buffered ============
__device__ void vgemm_job(const float* __restrict__ A, const float* __restrict__ Bm,
                          float* __restrict__ C, int bi, int bj, int t, char* sbuf) {
    float* Xs = (float*)sbuf;        // [16][68]
    float* Bs = Xs + 16 * 68;        // [16][68]
    int lrow = t >> 2, lk4 = (t & 3) * 4;
    int krow = t >> 4, jc = (t & 15) * 4;
    int tm = (t >> 4) * 4, tn = (t & 15) * 4;
    float acc[4][4] = {};
    float4 av = *(const float4*)(A + (size_t)(bi * 64 + lrow) * 512 + lk4);
    float4 bv = *(const float4*)(Bm + (size_t)krow * 512 + bj * 64 + jc);
    for (int c = 0; c < 32; c++) {
        Xs[(lk4 + 0) * 68 + lrow] = av.x; Xs[(lk4 + 1) * 68 + lrow] = av.y;
        Xs[(lk4 + 2) * 68 + lrow] = av.z; Xs[(lk4 + 3) * 68 + lrow] = av.w;
        *(float4*)&Bs[krow * 68 + jc] = bv;
        if (c < 31) {   // prefetch next chunk while this one computes
            int k0 = (c + 1) * 16;
            av = *(const float4*)(A + (size_t)(bi * 64 + lrow) * 512 + k0 + lk4);
            bv = *(const float4*)(Bm + (size_t)(k0 + krow) * 512 + bj * 64 + jc);
        }
        __syncthreads();
#pragma unroll
        for (int kk = 0; kk < 16; kk++) {
            float4 xa = *(const float4*)&Xs[kk * 68 + tm];
            float4 wb = *(const float4*)&Bs[kk * 68 + tn];
            float xr[4] = {xa.x, xa.y, xa.z, xa.w};
            float wr[4] = {wb.x, wb.y, wb.z, wb.w};
#pragma unroll
            for (int ii = 0; ii < 4; ii++)
#pragma unroll
                for (int jj = 0; jj < 4; jj++)
                    acc[ii][jj] = fmaf(xr[ii], wr[jj], acc[ii][jj]);
        }
        __syncthreads();
    }
    for (int ii = 0; ii < 4; ii++) {
        float4 o = {acc[ii][0], acc[ii][1], acc[ii][2], acc[ii][3]};
        *(float4*)(C + (size_t)(bi * 64 + tm + ii) * 512 + bj * 64 + tn) = o;
    }
}

// ============ job: coalesced matvec(s), 64 outputs per block ============
// vout[d] = W[d,:]@vin (+badd) (+ W2[d,:]@vin2). vin==null -> row-sum of W.
__device__ void mv_cw(const float* __restrict__ W, const float* __restrict__ vin,
                      const float* __restrict__ badd,
                      const float* __restrict__ W2, const float* __restrict__ vin2,
                      float* __restrict__ vout, int jb, int t, char* sbuf) {
    float* vs = (float*)sbuf;      // 1024 floats
    if (t < 128) {
        float4 one = make_float4(1.f, 1.f, 1.f, 1.f);
        ((float4*)vs)[t] = vin ? ((const float4*)vin)[t] : one;
    } else if (W2) {
        ((float4*)(vs + 512))[t - 128] = ((const float4*)vin2)[t - 128];
    }
    __syncthreads();
    int w = t >> 6, lane = t & 63;
    for (int o = 0; o < 16; o++) {
        int d = jb * 64 + w * 16 + o;
        const float* row = W + (size_t)d * 512;
        float4 v1 = *(const float4*)(row + lane * 4);
        float4 v2 = *(const float4*)(row + 256 + lane * 4);
        const float* va = vs + lane * 4;
        const float* vb = vs + 256 + lane * 4;
        float p = v1.x * va[0] + v1.y * va[1] + v1.z * va[2] + v1.w * va[3]
                + v2.x * vb[0] + v2.y * vb[1] + v2.z * vb[2] + v2.w * vb[3];
        if (W2) {
            const float* row2 = W2 + (size_t)d * 512;
            float4 u1 = *(const float4*)(row2 + lane * 4);
            float4 u2 = *(const float4*)(row2 + 256 + lane * 4);
            const float* wa = vs + 512 + lane * 4;
            const float* wb = vs + 768 + lane * 4;
            p += u1.x * wa[0] + u1.y * wa[1] + u1.z * wa[2] + u1.w * wa[3]
               + u2.x * wb[0] + u2.y * wb[1] + u2.z * wb[2] + u2.w * wb[3];
        }
        p = wred64(p);
        if (lane == 0) vout[d] = p + (badd ? badd[d] : 0.f);
    }
}

// ============ job: Out[64x512] = A[64x512] @ W[512x512]^T, coalesced+LDS ============
// 16 d's per block (32 blocks/matrix). mode 0 plain, 1 batch-BN+relu, 2 +stats.
__device__ void densek_job(const float* __restrict__ A, const float* __restrict__ W,
                           const float* __restrict__ bias, float* __restrict__ Out,
                           int jb, int t, char* sbuf, int mode, float* __restrict__ s_acc) {
    float* As = (float*)sbuf;          // [128][66] transposed: As[k][b]
    float* Ws = As + 128 * 66;         // [16][132]
    float* red = Ws + 16 * 132;        // [8]
    int d0 = jb * 16;
    int b = t & 63, dg = t >> 6;
    float acc[4] = {0.f, 0.f, 0.f, 0.f};
    for (int c = 0; c < 4; c++) {
        int k0 = c * 128;
#pragma unroll
        for (int r = 0; r < 8; r++) {
            int p = t + r * 256;
            int row = p >> 5, c4 = p & 31;
            float4 vv = *(const float4*)(A + (size_t)row * 512 + k0 + c4 * 4);
            As[(c4 * 4 + 0) * 66 + row] = vv.x;
            As[(c4 * 4 + 1) * 66 + row] = vv.y;
            As[(c4 * 4 + 2) * 66 + row] = vv.z;
            As[(c4 * 4 + 3) * 66 + row] = vv.w;
        }
#pragma unroll
        for (int r = 0; r < 2; r++) {
            int p = t + r * 256;
            int drow = p >> 5, c4 = p & 31;
            *(float4*)(Ws + drow * 132 + c4 * 4) =
                *(const float4*)(W + (size_t)(d0 + drow) * 512 + k0 + c4 * 4);
        }
        __syncthreads();
#pragma unroll 4
        for (int k = 0; k < 128; k += 4) {
            float x0 = As[(k + 0) * 66 + b], x1 = As[(k + 1) * 66 + b];
            float x2 = As[(k + 2) * 66 + b], x3 = As[(k + 3) * 66 + b];
#pragma unroll
            for (int i = 0; i < 4; i++) {
                float4 wv = *(const float4*)(Ws + (dg + i * 4) * 132 + k);
                acc[i] = fmaf(x0, wv.x, fmaf(x1, wv.y, fmaf(x2, wv.z, fmaf(x3, wv.w, acc[i]))));
            }
        }
        __syncthreads();
    }
    float s = 0.f, s2 = 0.f;
#pragma unroll
    for (int i = 0; i < 4; i++) {
        int d = d0 + dg + i * 4;
        float val = acc[i] + (bias ? bias[d] : 0.f);
        if (mode == 1) {
            float sv = __shfl(wred64(val), 0, 64);
            float sv2 = __shfl(wred64(val * val), 0, 64);
            float m = sv * (1.f / 64.f);
            float var = sv2 * (1.f / 64.f) - m * m;
            val = fmaxf((val - m) / sqrtf(var + EPSC), 0.f);
        }
        Out[b * 512 + d] = val;
        s += val; s2 = fmaf(val, val, s2);
    }
    if (mode == 2) {
        s = wred64(s); s2 = wred64(s2);
        if ((t & 63) == 0) { red[dg * 2] = s; red[dg * 2 + 1] = s2; }
        __syncthreads();
        if (t == 0) {
            atomicAdd(s_acc,     red[0] + red[2] + red[4] + red[6]);
            atomicAdd(s_acc + 1, red[1] + red[3] + red[5] + red[7]);
        }
    }
}

// ============ D1: weight-chain + gf + vectors + zero ============
__global__ __launch_bounds__(256) void d1_k(const float* __restrict__ x,
        const float* __restrict__ av_w, const float* __restrict__ fv_w,
        const float* __restrict__ fv_b, const float* __restrict__ av_b,
        const float* __restrict__ ep_w, const float* __restrict__ E1,
        float* __restrict__ ws) {
    __shared__ __align__(16) char sbuf[8704];
    int blk = blockIdx.x, t = threadIdx.x;
    if (blk < 64) {
        vgemm_job(av_w, fv_w, ws + T1_OFF, blk >> 3, blk & 7, t, sbuf);
    } else if (blk < 128) {
        int jb = blk - 64;
        vgemm_job(E1, ep_w, ws + WE_OFF, jb >> 3, jb & 7, t, sbuf);
    } else if (blk < 144) {
        int jb = blk - 128;
        float* gf = ws + GF_OFF;
        for (int p = 0; p < 8; p++) {
            int q = jb * 2048 + p * 256 + t;
            int b = q >> 9, d = q & 511;
            const float* pp = x + (size_t)b * 13824 + d;
            float s = 0.f;
#pragma unroll
            for (int n = 0; n < 27; n++) s += pp[n << 9];
            gf[q] = s * (1.0f / 27.0f);
        }
    } else if (blk < 152) {
        mv_cw(av_w, fv_b, av_b, nullptr, nullptr, ws + BC0_OFF, blk - 144, t, sbuf);
    } else if (blk < 160) {
        mv_cw(E1, nullptr, nullptr, nullptr, nullptr, ws + RE1_OFF, blk - 152, t, sbuf);
    } else {
        float* pac = ws + PAC_OFF;
        float* ST = ws + ST_OFF;
        for (int q = t; q < 729; q += 256) pac[q] = 0.f;
        if (t < 112) ST[108 + t] = 0.f;
    }
}

// ============ D2 jobs: gram + acsum (from R5, proven) ============
__device__ void gram_job(const float* __restrict__ Yb, float* __restrict__ pac,
                         int b, int t, char* sbuf) {
    float* As = (float*)sbuf;        // [27][132]
    float* Cs = As + 27 * 132;
    float a0 = 0, a1 = 0, a2 = 0;
    int i = t / 9, j0 = (t % 9) * 3;
    for (int dc = 0; dc < 4; dc++) {
        const float* base = Yb + (size_t)b * 27 * 2048 + dc * 128;
        for (int id = t; id < 864; id += 256) {
            int row = id >> 5, c4 = (id & 31) << 2;
            *(float4*)&As[row * 132 + c4] = *(const float4*)(base + (size_t)row * 2048 + c4);
            *(float4*)&Cs[row * 132 + c4] = *(const float4*)(base + (size_t)row * 2048 + 512 + c4);
        }
        __syncthreads();
        if (t < 243) {
#pragma unroll
            for (int k = 0; k < 128; k += 4) {
                float4 av = *(const float4*)&As[i * 132 + k];
                float4 c0 = *(const float4*)&Cs[j0 * 132 + k];
                float4 c1 = *(const float4*)&Cs[(j0 + 1) * 132 + k];
                float4 c2 = *(const float4*)&Cs[(j0 + 2) * 132 + k];
                a0 += av.x * c0.x + av.y * c0.y + av.z * c0.z + av.w * c0.w;
                a1 += av.x * c1.x + av.y * c1.y + av.z * c1.z + av.w * c1.w;
                a2 += av.x * c2.x + av.y * c2.y + av.z * c2.z + av.w * c2.w;
            }
        }
        __syncthreads();
    }
    if (t < 243) {
        atomicAdd(pac + i * 27 + j0, a0);
        atomicAdd(pac + i * 27 + j0 + 1, a1);
        atomicAdd(pac + i * 27 + j0 + 2, a2);
    }
}

__device__ void acsum_job(const float* __restrict__ Yb, float* __restrict__ ST,
                          int ia, int t, char* sbuf) {
    int i = ia < 27 ? ia : ia - 27;
    int off = ia < 27 ? 0 : 512;
    float s = 0, s2 = 0;
    for (int q = t; q < 32768; q += 256) {
        int b = q >> 9, d = q & 511;
        float v = Yb[(size_t)(b * 27 + i) * 2048 + off + d];
        s += v; s2 = fmaf(v, v, s2);
    }
    s = wred64(s); s2 = wred64(s2);
    float* p = (float*)sbuf;
    int wv_ = t >> 6;
    if ((t & 63) == 0) { p[wv_ * 2] = s; p[wv_ * 2 + 1] = s2; }
    __syncthreads();
    if (t == 0) {
        float S = p[0] + p[2] + p[4] + p[6];
        float S2 = p[1] + p[3] + p[5] + p[7];
        if (ia < 27) { ST[ia] = S; ST[27 + ia] = S2; }
        else { ST[54 + (ia - 27)] = S; ST[81 + (ia - 27)] = S2; }
    }
}

__global__ __launch_bounds__(256) void d2_k(const float* __restrict__ gl_w,
        const float* __restrict__ gl_b, const float* __restrict__ ep_w,
        const float* __restrict__ ep_b, const float* __restrict__ E1,
        float* __restrict__ ws) {
    __shared__ __align__(16) char sbuf[42400];
    int blk = blockIdx.x, t = threadIdx.x;
    if (blk < 32) {
        densek_job(ws + GF_OFF, gl_w, gl_b, ws + G_OFF, blk, t, sbuf, 1, nullptr);
    } else if (blk < 96) {
        int jb = blk - 32;    // Wc = ep_w @ T1
        vgemm_job(ep_w, ws + T1_OFF, ws + WC_OFF, jb >> 3, jb & 7, t, sbuf);
    } else if (blk < 160) {
        int jb = blk - 96;    // Wd = We @ T1
        vgemm_job(ws + WE_OFF, ws + T1_OFF, ws + WD_OFF, jb >> 3, jb & 7, t, sbuf);
    } else if (blk < 224) {
        gram_job(ws + YB_OFF, ws + PAC_OFF, blk - 160, t, sbuf);
    } else if (blk < 278) {
        acsum_job(ws + YB_OFF, ws + ST_OFF, blk - 224, t, sbuf);
    } else if (blk < 286) {
        mv_cw(ep_w, ws + BC0_OFF, ep_b, nullptr, nullptr, ws + BC_OFF, blk - 278, t, sbuf);
    } else {
        mv_cw(ws + WE_OFF, ws + BC0_OFF, nullptr, E1, ep_b, ws + BCE_OFF, blk - 286, t, sbuf);
    }
}

// ============ D3: e0 = g@Wc^T + bc (stats); f0 = g@Wd^T + bcE ============
__global__ __launch_bounds__(256) void d3_k(float* __restrict__ ws) {
    __shared__ __align__(16) char sbuf[42400];
    int blk = blockIdx.x, t = threadIdx.x;
    if (blk < 32) {
        densek_job(ws + G_OFF, ws + WC_OFF, ws + BC_OFF, ws + E0_OFF,
                   blk, t, sbuf, 2, ws + ST_OFF + 164);
    } else {
        densek_job(ws + G_OFF, ws + WD_OFF, ws + BCE_OFF, ws + F0_OFF,
                   blk - 32, t, sbuf, 0, nullptr);
    }
}

// ============ D4: sae/sce (216 blocks) + eE/eN/se (32 blocks) ============
__global__ __launch_bounds__(256) void d4_k(float* __restrict__ ws) {
    __shared__ __align__(16) char sbuf[64];
    int blk = blockIdx.x, t = threadIdx.x;
    const float* Yb = ws + YB_OFF;
    const float* e0 = ws + E0_OFF;
    const float* f0 = ws + F0_OFF;
    const float* rE1 = ws + RE1_OFF;
    float* ST = ws + ST_OFF;
    float m = ST[164] * (1.f / 32768.f);
    float var = ST[165] * (1.f / 32768.f) - m * m;
    float rs = 1.f / sqrtf(var + EPSC);
    float* p = (float*)sbuf;
    int wv_ = t >> 6;
    if (blk < 216) {
        int i = blk % 27, bg = blk / 27;
        float sae = 0.f, sce = 0.f;
        for (int idx = t; idx < 4096; idx += 256) {
            int bb = bg * 8 + (idx >> 9), d = idx & 511;
            float e = rs * (f0[bb * 512 + d] - m * rE1[d]);
            size_t base = (size_t)(bb * 27 + i) * 2048 + d;
            sae = fmaf(Yb[base], e, sae);
            sce = fmaf(Yb[base + 512], e, sce);
        }
        sae = wred64(sae); sce = wred64(sce);
        if ((t & 63) == 0) { p[wv_ * 2] = sae; p[wv_ * 2 + 1] = sce; }
        __syncthreads();
        if (t == 0) {
            atomicAdd(ST + 108 + i, p[0] + p[2] + p[4] + p[6]);
            atomicAdd(ST + 135 + i, p[1] + p[3] + p[5] + p[7]);
        }
    } else {
        float* eE = ws + EE_OFF;
        float* eN = ws + EN_OFF;
        int base = (blk - 216) * 1024;
        float se = 0.f, se2 = 0.f;
#pragma unroll
        for (int r = 0; r < 4; r++) {
            int q = base + r * 256 + t;
            float e = rs * (f0[q] - m * rE1[q & 511]);
            eE[q] = e;
            eN[q] = (e0[q] - m) * rs;
            se += e; se2 = fmaf(e, e, se2);
        }
        se = wred64(se); se2 = wred64(se2);
        if ((t & 63) == 0) { p[wv_ * 2] = se; p[wv_ * 2 + 1] = se2; }
        __syncthreads();
        if (t == 0) {
            atomicAdd(ST + 162, p[0] + p[2] + p[4] + p[6]);
            atomicAdd(ST + 163, p[1] + p[3] + p[5] + p[7]);
        }
    }
}

// ============ D5: fuse gate/softmax/aggregate (proven R5) ============
__global__ __launch_bounds__(256) void d5_k(float* __restrict__ ws) {
    __shared__ __align__(16) char sbuf[5888];
    int blk = blockIdx.x, t = threadIdx.x;
    const float* Yb = ws + YB_OFF;
    const float* eE = ws + EE_OFF;
    const float* eN = ws + EN_OFF;
    const float* pac = ws + PAC_OFF;
    float* ST = ws + ST_OFF;
    float* xn = ws + XN_OFF;
    float* pbn_acc = ST + 166;
    float* rstL = (float*)sbuf;      // 736
    float* pmsL = rstL + 736;
    float Se = ST[162], Se2 = ST[163];
    const float inv = 1.f / 32768.f;
    for (int id = t; id < 729; id += 256) {
        int i = id / 27, j = id - i * 27;
        float m = (ST[i] + ST[54 + j] + Se) * inv;
        float S2 = ST[27 + i] + ST[81 + j] + Se2 + 2.f * (pac[id] + ST[108 + i] + ST[135 + j]);
        float var = S2 * inv - m * m;
        float rst = 1.f / sqrtf(var + EPSC);
        rstL[id] = rst; pmsL[id] = -m * rst;
    }
    __syncthreads();
    int b = blk >> 2, ds4 = (blk & 3) * 128;
    int j = t & 127, ih = t >> 7;
    float ev = eE[b * 512 + ds4 + j], env = eN[b * 512 + ds4 + j];
    float cr[27], ur[27];
#pragma unroll
    for (int jj = 0; jj < 27; ++jj) {
        size_t rb = (size_t)(b * 27 + jj) * 2048 + ds4 + j;
        cr[jj] = Yb[rb + 512];
        ur[jj] = Yb[rb + 1024];
    }
    const float L2E = 1.4426950408889634f;
    int i0 = ih ? 14 : 0, i1 = ih ? 27 : 14;
    for (int i = i0; i < i1; ++i) {
        size_t rb = (size_t)(b * 27 + i) * 2048 + ds4 + j;
        float t1 = Yb[rb] + ev;
        const float* prst = rstL + i * 27;
        const float* ppms = pmsL + i * 27;
        float num = 0.f, den = 0.f;
#pragma unroll
        for (int jj = 0; jj < 27; ++jj) {
            float bn = fmaf(t1 + cr[jj], prst[jj], ppms[jj]);
            float r = fmaxf(bn, 0.f);
            float z = env + r;
            float tt = __builtin_amdgcn_exp2f(z * -L2E);
            float sg = __builtin_amdgcn_rcpf(1.f + tt);
            float w2 = __builtin_amdgcn_exp2f(sg * L2E);
            den += w2;
            num = fmaf(w2, ur[jj], num);
        }
        xn[(size_t)b * 13824 + i * 512 + ds4 + j] =
            Yb[rb + 1536] + num * __builtin_amdgcn_rcpf(den) * (1.f / 27.f);
    }
    __syncthreads();
    if (t < 27) {
        float s = 0, s2 = 0;
        const float4* xp = (const float4*)(xn + (size_t)b * 13824 + t * 512 + ds4);
        for (int q = 0; q < 32; q++) {
            float4 v = xp[q];
            s += (v.x + v.y) + (v.z + v.w);
            s2 += v.x * v.x + v.y * v.y + v.z * v.z + v.w * v.w;
        }
        atomicAdd(pbn_acc + t * 2, s);
        atomicAdd(pbn_acc + t * 2 + 1, s2);
    }
}

// ============ D6: per-n BN + residual relu ============
__global__ __launch_bounds__(256) void d6_k(const float* __restrict__ x,
        float* __restrict__ ws, float* __restrict__ out) {
    __shared__ __align__(16) char sbuf[256];
    int blk = blockIdx.x, t = threadIdx.x;
    const float* xn = ws + XN_OFF;
    const float* pbn_acc = ws + ST_OFF + 166;
    float* m2L = (float*)sbuf;
    float* rs2L = m2L + 32;
    if (t < 27) {
        float S = pbn_acc[t * 2], S2 = pbn_acc[t * 2 + 1];
        float m = S * (1.f / 32768.f);
        float var = S2 * (1.f / 32768.f) - m * m;
        m2L[t] = m; rs2L[t] = 1.f / sqrtf(var + EPSC);
    }
    __syncthreads();
    int b = blk >> 2, ds4 = (blk & 3) * 128;
    int j = t & 127, nh = t >> 7;
    int n0 = nh * 14, n1 = nh ? 27 : 14;
    for (int n = n0; n < n1; ++n) {
        size_t xi = (size_t)b * 13824 + n * 512 + ds4 + j;
        out[xi] = fmaxf(fmaf(xn[xi] - m2L[n], rs2L[n], x[xi]), 0.f);
    }
}

extern "C" void kernel_launch(void* const* d_in, const int* in_sizes, int n_in,
                              void* d_out, int out_size, void* d_ws, size_t ws_size,
                              hipStream_t stream) {
    const float* x    = (const float*)d_in[0];
    const float* gl_w = (const float*)d_in[1];
    const float* gl_b = (const float*)d_in[2];
    const float* fv_w = (const float*)d_in[7];
    const float* fv_b = (const float*)d_in[8];
    const float* av_w = (const float*)d_in[13];
    const float* av_b = (const float*)d_in[14];
    const float* ep_w = (const float*)d_in[15];
    const float* ep_b = (const float*)d_in[16];
    const float* U1   = (const float*)d_in[17];
    const float* V1   = (const float*)d_in[18];
    const float* A1   = (const float*)d_in[19];
    const float* B1   = (const float*)d_in[20];
    const float* E1   = (const float*)d_in[21];
    float* out = (float*)d_out;
    float* ws = (float*)d_ws;

    d0_k<<<224, 256, 0, stream>>>(x, A1, B1, V1, U1, ws + YB_OFF);
    d1_k<<<161, 256, 0, stream>>>(x, av_w, fv_w, fv_b, av_b, ep_w, E1, ws);
    d2_k<<<294, 256, 0, stream>>>(gl_w, gl_b, ep_w, ep_b, E1, ws);
    d3_k<<<64, 256, 0, stream>>>(ws);
    d4_k<<<248, 256, 0, stream>>>(ws);
    d5_k<<<256, 256, 0, stream>>>(ws);
    d6_k<<<256, 256, 0, stream>>>(x, ws, out);
}